// Round 8
// baseline (755.859 us; speedup 1.0000x reference)
//
#include <hip/hip_runtime.h>
#include <hip/hip_bf16.h>
#include <math.h>

// Problem constants
#define B_   16
#define L_   196
#define FD_  2048
#define N_   1000
#define WD_  300
#define HD_  512
#define DD_  5
#define E_   50000
#define TMAX_ 5
#define NIMG_ 1000

typedef __attribute__((ext_vector_type(8))) short bf16x8;
typedef __attribute__((ext_vector_type(4))) float f32x4;

__device__ __forceinline__ short bf_hi(float x) {
    unsigned u = __float_as_uint(x);
    unsigned r = u + 0x7fffu + ((u >> 16) & 1u);
    return (short)(r >> 16);
}
__device__ __forceinline__ float bf2f_(short s) {
    return __uint_as_float(((unsigned)(unsigned short)s) << 16);
}

// ---------------------------------------------------------------------------
// init: zero prop + Pk + out_attn, preset Ht0 with bf2
// ---------------------------------------------------------------------------
#define PK_ELEMS (3136 * 1024)
__global__ void init_all(float* __restrict__ prop, float* __restrict__ Pk,
                         float* __restrict__ attn, float* __restrict__ Ht0,
                         const float* __restrict__ bf2)
{
    int i = blockIdx.x * blockDim.x + threadIdx.x;
    if (i < N_ * N_) prop[i] = 0.f;
    if (i < PK_ELEMS) Pk[i] = 0.f;
    if (i < B_ * N_ * L_) attn[i] = 0.f;
    if (i < N_ * B_ * DD_) Ht0[i] = bf2[i % DD_];
}

// ---------------------------------------------------------------------------
// fp32 -> bf16 hi/lo planes, elementwise (4 per thread)
// ---------------------------------------------------------------------------
__global__ void conv_split(const float* __restrict__ in, short* __restrict__ outH,
                           short* __restrict__ outL, int n4)
{
    int i = blockIdx.x * blockDim.x + threadIdx.x;
    if (i >= n4) return;
    float4 v = *(const float4*)(in + i * 4);
    float xs[4] = {v.x, v.y, v.z, v.w};
    short h[4], l[4];
    #pragma unroll
    for (int j = 0; j < 4; j++) {
        h[j] = bf_hi(xs[j]);
        if (outL) l[j] = bf_hi(xs[j] - bf2f_(h[j]));
    }
    *(int2*)(outH + i * 4) = *(int2*)h;
    if (outL) *(int2*)(outL + i * 4) = *(int2*)l;
}

// ---------------------------------------------------------------------------
// Transpose + convert: in fp32 [K][N] -> outH (and optionally outL) bf16 [N][K]
// ---------------------------------------------------------------------------
__global__ __launch_bounds__(256) void transconv(
    const float* __restrict__ in, short* __restrict__ outH, short* __restrict__ outL,
    int K, int N)
{
    __shared__ float tile[32][33];
    int k0 = blockIdx.x * 32, n0 = blockIdx.y * 32;
    int t = threadIdx.x;
    int tr = t >> 5, tc = t & 31;
    #pragma unroll
    for (int i = 0; i < 4; i++) {
        int k = k0 + tr + i * 8, n = n0 + tc;
        tile[tr + i * 8][tc] = (k < K && n < N) ? in[(long)k * N + n] : 0.f;
    }
    __syncthreads();
    #pragma unroll
    for (int i = 0; i < 4; i++) {
        int n = n0 + tr + i * 8, k = k0 + tc;
        if (n < N && k < K) {
            float x = tile[tc][tr + i * 8];
            short hi = bf_hi(x);
            outH[(long)n * K + k] = hi;
            if (outL) outL[(long)n * K + k] = bf_hi(x - bf2f_(hi));
        }
    }
}

// ---------------------------------------------------------------------------
__device__ __forceinline__ void load8s(const short* __restrict__ rowp, bool rowok,
                                       int gk, int K, short* tmp)
{
    if (rowok && gk + 8 <= K) {
        *(int2*)&tmp[0] = *(const int2*)(rowp + gk);
        *(int2*)&tmp[4] = *(const int2*)(rowp + gk + 4);
    } else {
        #pragma unroll
        for (int j = 0; j < 8; j++)
            tmp[j] = (rowok && gk + j < K) ? rowp[gk + j] : (short)0;
    }
}

// ---------------------------------------------------------------------------
// MFMA GEMM v4. A,B bf16 planes [rows][K] (hi + optional lo). Block tile
// 128x64, 256 threads = 4 waves (each 32 rows x 64 cols), BK=32, 16x16x32.
// SPLIT: AhBh + AlBh + AhBl fused in-loop.
// OUT_SPLIT: hi/lo planes (+bias).
// OUT_PART : split-K partial, z = k-chunk, atomicAdd fp32 into C0 [M][N].
// OUT_PARTB: z = batch*2 + kchunk, atomicAdd fp32 into C0 + batch*sC.
// OUT_H0   : h1 fused epilogue: relu(v + bias[n]) reduced with W2[n][5]
//            across the 64-col tile, atomicAdd into C0 = h0t [M][16][5] @ z.
// ---------------------------------------------------------------------------
#define OUT_SPLIT 1
#define OUT_PART  2
#define OUT_PARTB 3
#define OUT_H0    4

template<int OUTMODE, bool SPLIT>
__global__ __launch_bounds__(256) void mm4(
    const short* __restrict__ Ah, const short* __restrict__ Al,
    const short* __restrict__ Bh, const short* __restrict__ Bl,
    const float* __restrict__ bias, void* __restrict__ C0, void* __restrict__ C1,
    const float* __restrict__ W2,
    int M, int N, int K, long sA, long sB, long sC, int kspl)
{
    __shared__ short AsH[128][40];
    __shared__ short AsL[SPLIT ? 128 : 1][40];
    __shared__ short BsH[64][40];
    __shared__ short BsL[SPLIT ? 64 : 1][40];
    int z = blockIdx.z;
    int kbeg = 0, kend = K;
    int zb = 0, kc = 0;
    if (OUTMODE == OUT_PART) {
        kbeg = z * kspl; kend = min(K, kbeg + kspl);
    } else if (OUTMODE == OUT_PARTB) {
        zb = z >> 1; kc = z & 1;
        kbeg = kc * kspl; kend = min(K, kbeg + kspl);
        Bh += (long)zb * sB;
        if (SPLIT) Bl += (long)zb * sB;
    } else {
        Ah += (long)z * sA; Bh += (long)z * sB;
        if (SPLIT) { Al += (long)z * sA; Bl += (long)z * sB; }
    }
    int t = threadIdx.x;
    int lane = t & 63, w = t >> 6;
    int q = lane >> 4, r = lane & 15;
    int row0 = blockIdx.y * 128, col0 = blockIdx.x * 64;
    f32x4 zero4 = {0.f, 0.f, 0.f, 0.f};
    f32x4 acc[2][4];
    #pragma unroll
    for (int i = 0; i < 2; i++)
        #pragma unroll
        for (int j = 0; j < 4; j++) acc[i][j] = zero4;

    int arow = t >> 1, akc = (t & 1) * 16;
    int brow = t >> 2, bkc = (t & 3) * 8;
    for (int k0 = kbeg; k0 < kend; k0 += 32) {
        short tmp[8];
        {
            int gm = row0 + arow;
            bool ok = gm < M;
            const short* ap = Ah + (long)gm * K;
            load8s(ap, ok, k0 + akc, kend, tmp);
            *(int4*)&AsH[arow][akc] = *(int4*)tmp;
            load8s(ap, ok, k0 + akc + 8, kend, tmp);
            *(int4*)&AsH[arow][akc + 8] = *(int4*)tmp;
            if (SPLIT) {
                const short* alp = Al + (long)gm * K;
                load8s(alp, ok, k0 + akc, kend, tmp);
                *(int4*)&AsL[arow][akc] = *(int4*)tmp;
                load8s(alp, ok, k0 + akc + 8, kend, tmp);
                *(int4*)&AsL[arow][akc + 8] = *(int4*)tmp;
            }
        }
        {
            int gn = col0 + brow;
            bool ok = gn < N;
            load8s(Bh + (long)gn * K, ok, k0 + bkc, kend, tmp);
            *(int4*)&BsH[brow][bkc] = *(int4*)tmp;
            if (SPLIT) {
                load8s(Bl + (long)gn * K, ok, k0 + bkc, kend, tmp);
                *(int4*)&BsL[brow][bkc] = *(int4*)tmp;
            }
        }
        __syncthreads();
        bf16x8 ah0 = *(const bf16x8*)&AsH[w * 32 + r][q * 8];
        bf16x8 ah1 = *(const bf16x8*)&AsH[w * 32 + 16 + r][q * 8];
        bf16x8 al0, al1;
        if (SPLIT) {
            al0 = *(const bf16x8*)&AsL[w * 32 + r][q * 8];
            al1 = *(const bf16x8*)&AsL[w * 32 + 16 + r][q * 8];
        }
        #pragma unroll
        for (int ct = 0; ct < 4; ct++) {
            bf16x8 bh = *(const bf16x8*)&BsH[ct * 16 + r][q * 8];
            acc[0][ct] = __builtin_amdgcn_mfma_f32_16x16x32_bf16(ah0, bh, acc[0][ct], 0, 0, 0);
            acc[1][ct] = __builtin_amdgcn_mfma_f32_16x16x32_bf16(ah1, bh, acc[1][ct], 0, 0, 0);
            if (SPLIT) {
                acc[0][ct] = __builtin_amdgcn_mfma_f32_16x16x32_bf16(al0, bh, acc[0][ct], 0, 0, 0);
                acc[1][ct] = __builtin_amdgcn_mfma_f32_16x16x32_bf16(al1, bh, acc[1][ct], 0, 0, 0);
                bf16x8 bl = *(const bf16x8*)&BsL[ct * 16 + r][q * 8];
                acc[0][ct] = __builtin_amdgcn_mfma_f32_16x16x32_bf16(ah0, bl, acc[0][ct], 0, 0, 0);
                acc[1][ct] = __builtin_amdgcn_mfma_f32_16x16x32_bf16(ah1, bl, acc[1][ct], 0, 0, 0);
            }
        }
        __syncthreads();
    }

    if (OUTMODE == OUT_H0) {
        // relu(v + bias[n]) * W2[n][d], reduce over the block's 64 n-cols,
        // atomicAdd into h0t[m][z*5+d]  (h0t layout [node][16][5])
        float s[2][4][DD_];
        #pragma unroll
        for (int i = 0; i < 2; i++)
            #pragma unroll
            for (int reg = 0; reg < 4; reg++)
                #pragma unroll
                for (int d = 0; d < DD_; d++) s[i][reg][d] = 0.f;
        #pragma unroll
        for (int i = 0; i < 2; i++) {
            #pragma unroll
            for (int ct = 0; ct < 4; ct++) {
                int n = col0 + ct * 16 + r;
                float w2v[DD_];
                #pragma unroll
                for (int d = 0; d < DD_; d++) w2v[d] = W2[n * DD_ + d];
                float b1 = bias[n];
                #pragma unroll
                for (int reg = 0; reg < 4; reg++) {
                    int m = row0 + w * 32 + i * 16 + q * 4 + reg;
                    if (m >= M) continue;
                    float val = fmaxf(acc[i][ct][reg] + b1, 0.f);
                    #pragma unroll
                    for (int d = 0; d < DD_; d++) s[i][reg][d] = fmaf(val, w2v[d], s[i][reg][d]);
                }
            }
        }
        #pragma unroll
        for (int i = 0; i < 2; i++)
            #pragma unroll
            for (int reg = 0; reg < 4; reg++)
                #pragma unroll
                for (int d = 0; d < DD_; d++) {
                    float v = s[i][reg][d];
                    v += __shfl_xor(v, 1);
                    v += __shfl_xor(v, 2);
                    v += __shfl_xor(v, 4);
                    v += __shfl_xor(v, 8);
                    if (r == 0) {
                        int m = row0 + w * 32 + i * 16 + q * 4 + reg;
                        if (m < M)
                            atomicAdd(&((float*)C0)[(long)m * (B_ * DD_) + z * DD_ + d], v);
                    }
                }
        return;
    }

    #pragma unroll
    for (int i = 0; i < 2; i++) {
        #pragma unroll
        for (int ct = 0; ct < 4; ct++) {
            #pragma unroll
            for (int reg = 0; reg < 4; reg++) {
                int m = row0 + w * 32 + i * 16 + q * 4 + reg;
                int n = col0 + ct * 16 + r;
                if (m >= M || n >= N) continue;
                float v = acc[i][ct][reg];
                if (OUTMODE == OUT_PART) {
                    atomicAdd(&((float*)C0)[(long)m * N + n], v);
                } else if (OUTMODE == OUT_PARTB) {
                    atomicAdd(&((float*)C0)[(long)zb * sC + (long)m * N + n], v);
                } else { // OUT_SPLIT
                    if (bias) v += bias[n];
                    long idx = (long)m * N + n;
                    short hi = bf_hi(v);
                    ((short*)C0)[idx] = hi;
                    ((short*)C1)[idx] = bf_hi(v - bf2f_(hi));
                }
            }
        }
    }
}

// ---------------------------------------------------------------------------
// reduce/epilogue for fused keys+F1 split-K partials (Pk [3136][1024] fp32):
// n<512 -> keys hi/lo (+b_key); n>=512 -> F1^T bf16 [b][512][196]
// ---------------------------------------------------------------------------
__global__ void reduce_kf1(const float* __restrict__ Pk, const float* __restrict__ b_key,
                           short* __restrict__ keysH, short* __restrict__ keysL,
                           short* __restrict__ F1T)
{
    int gid = blockIdx.x * blockDim.x + threadIdx.x;
    if (gid >= PK_ELEMS / 4) return;
    long base = (long)gid * 4;
    int m = (int)(base >> 10);
    int n0 = (int)(base & 1023);
    float4 v4 = *(const float4*)(Pk + base);
    float vs[4] = {v4.x, v4.y, v4.z, v4.w};
    if (n0 < 512) {
        short hs[4], ls[4];
        #pragma unroll
        for (int j = 0; j < 4; j++) {
            float v = vs[j] + b_key[n0 + j];
            hs[j] = bf_hi(v);
            ls[j] = bf_hi(v - bf2f_(hs[j]));
        }
        *(int2*)(keysH + (long)m * 512 + n0) = *(int2*)hs;
        *(int2*)(keysL + (long)m * 512 + n0) = *(int2*)ls;
    } else {
        int b = m / 196, l = m - b * 196;
        #pragma unroll
        for (int j = 0; j < 4; j++) {
            int nf = n0 + j - 512;
            F1T[((long)b * 512 + nf) * 196 + l] = bf_hi(vs[j]);
        }
    }
}

// ---------------------------------------------------------------------------
// Edge MLP via MFMA: 64 edges x 256 units/block, K=600.
// ---------------------------------------------------------------------------
__global__ __launch_bounds__(256) void edge_mfma(
    const short* __restrict__ embedH, const int* __restrict__ edges,
    const short* __restrict__ Wr1T, const float* __restrict__ br1,
    const float* __restrict__ Wr2, const float* __restrict__ br2,
    float* __restrict__ prop)
{
    __shared__ short As[64][40];
    __shared__ short Bs[256][40];
    __shared__ int src[64], dst[64];
    __shared__ float part[64][5];
    int t = threadIdx.x;
    int e0 = blockIdx.x * 64;
    if (t < 64) {
        int e = e0 + t;
        src[t] = (e < E_) ? edges[e] : 0;
        dst[t] = (e < E_) ? edges[E_ + e] : 0;
    }
    __syncthreads();
    int lane = t & 63, w = t >> 6, q = lane >> 4, r = lane & 15;
    f32x4 zero4 = {0.f, 0.f, 0.f, 0.f};
    f32x4 acc[4][4];
    #pragma unroll
    for (int i = 0; i < 4; i++)
        #pragma unroll
        for (int j = 0; j < 4; j++) acc[i][j] = zero4;

    for (int ks = 0; ks < 19; ks++) {
        int k0 = ks * 32;
        {
            int arow = t >> 2, kc = (t & 3) * 8;
            int gk0 = k0 + kc;
            int sn = src[arow], dn = dst[arow];
            short tmp[8];
            if (gk0 + 8 <= 300) {
                const short* p = embedH + (long)sn * 300 + gk0;
                *(int2*)&tmp[0] = *(const int2*)p;
                *(int2*)&tmp[4] = *(const int2*)(p + 4);
            } else if (gk0 >= 300 && gk0 + 8 <= 600) {
                const short* p = embedH + (long)dn * 300 + (gk0 - 300);
                *(int2*)&tmp[0] = *(const int2*)p;
                *(int2*)&tmp[4] = *(const int2*)(p + 4);
            } else {
                #pragma unroll
                for (int j = 0; j < 8; j++) {
                    int gk = gk0 + j;
                    short v = 0;
                    if (gk < 300) v = embedH[(long)sn * 300 + gk];
                    else if (gk < 600) v = embedH[(long)dn * 300 + gk - 300];
                    tmp[j] = v;
                }
            }
            *(int4*)&As[arow][kc] = *(int4*)&tmp[0];
        }
        #pragma unroll
        for (int i = 0; i < 4; i++) {
            int n = i * 64 + (t >> 2), kc = (t & 3) * 8;
            int gk0 = k0 + kc;
            short tmp[8];
            if (gk0 + 8 <= 600) {
                const short* p = Wr1T + (long)n * 600 + gk0;
                *(int2*)&tmp[0] = *(const int2*)p;
                *(int2*)&tmp[4] = *(const int2*)(p + 4);
            } else {
                #pragma unroll
                for (int j = 0; j < 8; j++) tmp[j] = 0;
            }
            *(int4*)&Bs[n][kc] = *(int4*)&tmp[0];
        }
        __syncthreads();
        bf16x8 af[4], bfr[4];
        #pragma unroll
        for (int rt = 0; rt < 4; rt++) af[rt] = *(const bf16x8*)&As[rt * 16 + r][q * 8];
        #pragma unroll
        for (int ct = 0; ct < 4; ct++) bfr[ct] = *(const bf16x8*)&Bs[w * 64 + ct * 16 + r][q * 8];
        #pragma unroll
        for (int rt = 0; rt < 4; rt++)
            #pragma unroll
            for (int ct = 0; ct < 4; ct++)
                acc[rt][ct] = __builtin_amdgcn_mfma_f32_16x16x32_bf16(af[rt], bfr[ct], acc[rt][ct], 0, 0, 0);
        __syncthreads();
    }
    float b1v[4], w2v[4];
    #pragma unroll
    for (int ct = 0; ct < 4; ct++) {
        int u = w * 64 + ct * 16 + r;
        b1v[ct] = br1[u];
        w2v[ct] = Wr2[u];
    }
    #pragma unroll
    for (int rt = 0; rt < 4; rt++) {
        #pragma unroll
        for (int reg = 0; reg < 4; reg++) {
            float s = 0.f;
            #pragma unroll
            for (int ct = 0; ct < 4; ct++)
                s = fmaf(fmaxf(acc[rt][ct][reg] + b1v[ct], 0.f), w2v[ct], s);
            s += __shfl_xor(s, 1);
            s += __shfl_xor(s, 2);
            s += __shfl_xor(s, 4);
            s += __shfl_xor(s, 8);
            if (r == 0) part[rt * 16 + q * 4 + reg][w] = s;
        }
    }
    __syncthreads();
    if (t < 64 && e0 + t < E_) {
        float s = part[t][0] + part[t][1] + part[t][2] + part[t][3];
        atomicAdd(&prop[(long)src[t] * N_ + dst[t]], tanhf(s + br2[0]));
    }
}

// ---------------------------------------------------------------------------
__global__ void pooled_kernel(const float* __restrict__ feats, float* __restrict__ pooled)
{
    int idx = blockIdx.x * blockDim.x + threadIdx.x;
    if (idx >= B_ * FD_) return;
    int b = idx / FD_, f = idx % FD_;
    const float* p = feats + (long)b * L_ * FD_ + f;
    float acc = 0.f;
    for (int l = 0; l < L_; l++) acc += p[(long)l * FD_];
    pooled[idx] = acc * (1.0f / L_);
}

// clf partials: P[ks][b*1000+n], no atomics (bias folded into ks==0)
__global__ void clf_partial(const float* __restrict__ pooled, const float* __restrict__ W,
                            const float* __restrict__ bias, float* __restrict__ P)
{
    int i = blockIdx.x * blockDim.x + threadIdx.x;
    int ks = blockIdx.y;
    if (i >= B_ * NIMG_) return;
    int b = i / NIMG_, n = i % NIMG_;
    const float* p = pooled + (long)b * FD_ + ks * 256;
    const float* w = W + (long)(ks * 256) * NIMG_ + n;
    float acc = (ks == 0) ? bias[n] : 0.f;
    #pragma unroll 4
    for (int k = 0; k < 256; k++) acc = fmaf(p[k], w[(long)k * NIMG_], acc);
    P[(long)ks * (B_ * NIMG_) + i] = acc;
}

// softmax over 1000 cols of sum of 8 partials -> dst
__global__ void softmax_img(const float* __restrict__ P, float* __restrict__ dst, int rows)
{
    int gid = blockIdx.x * blockDim.x + threadIdx.x;
    int wave = gid >> 6, lane = gid & 63;
    if (wave >= rows) return;
    const int PER = (NIMG_ + 63) / 64;
    float v[PER];
    float m = -1e30f;
    int cnt = 0;
    for (int k = lane; k < NIMG_; k += 64) {
        float s = 0.f;
        #pragma unroll
        for (int ks = 0; ks < 8; ks++) s += P[(long)ks * (B_ * NIMG_) + wave * NIMG_ + k];
        v[cnt] = s; m = fmaxf(m, s); cnt++;
    }
    #pragma unroll
    for (int off = 32; off; off >>= 1) m = fmaxf(m, __shfl_xor(m, off));
    float s = 0.f;
    for (int i = 0; i < cnt; i++) { v[i] = expf(v[i] - m); s += v[i]; }
    #pragma unroll
    for (int off = 32; off; off >>= 1) s += __shfl_xor(s, off);
    float inv = 1.f / s;
    cnt = 0;
    for (int k = lane; k < NIMG_; k += 64) dst[(long)wave * NIMG_ + k] = v[cnt++] * inv;
}

// in-place row softmax over 196; emits bf16 copy
__global__ void softmax_attn(float* __restrict__ X, short* __restrict__ Xb, int rows)
{
    int gid = blockIdx.x * blockDim.x + threadIdx.x;
    int wave = gid >> 6, lane = gid & 63;
    if (wave >= rows) return;
    float* row = X + (long)wave * L_;
    const int PER = (L_ + 63) / 64;
    float v[PER];
    float m = -1e30f;
    int cnt = 0;
    for (int k = lane; k < L_; k += 64) { v[cnt] = row[k]; m = fmaxf(m, v[cnt]); cnt++; }
    #pragma unroll
    for (int off = 32; off; off >>= 1) m = fmaxf(m, __shfl_xor(m, off));
    float s = 0.f;
    for (int i = 0; i < cnt; i++) { v[i] = expf(v[i] - m); s += v[i]; }
    #pragma unroll
    for (int off = 32; off; off >>= 1) s += __shfl_xor(s, off);
    float inv = 1.f / s;
    cnt = 0;
    for (int k = lane; k < L_; k += 64) {
        float val = v[cnt++] * inv;
        row[k] = val;
        Xb[(long)wave * L_ + k] = bf_hi(val);
    }
}

// ---------------------------------------------------------------------------
// Recurrence step, one thread per output element (H [N][B*D=80]).
// ---------------------------------------------------------------------------
__global__ __launch_bounds__(320) void step_kernel(
    const float* __restrict__ prop, const float* __restrict__ Hin,
    float* __restrict__ Hout,
    const float* __restrict__ W_ih, const float* __restrict__ b_ih,
    const float* __restrict__ W_hh, const float* __restrict__ b_hh)
{
    __shared__ float msg[4][80];
    int t = threadIdx.x;
    int nl = t / 80, c = t - nl * 80;
    int n = blockIdx.x * 4 + nl;
    const float* pr = prop + (long)n * N_;
    const float* hc = Hin + c;
    float acc = 0.f;
    #pragma unroll 4
    for (int m4 = 0; m4 < N_; m4 += 4) {
        float4 pv = *(const float4*)(pr + m4);
        acc = fmaf(pv.x, hc[(long)(m4 + 0) * 80], acc);
        acc = fmaf(pv.y, hc[(long)(m4 + 1) * 80], acc);
        acc = fmaf(pv.z, hc[(long)(m4 + 2) * 80], acc);
        acc = fmaf(pv.w, hc[(long)(m4 + 3) * 80], acc);
    }
    msg[nl][c] = tanhf(acc);
    __syncthreads();
    if (t < 64) {
        int nl2 = t >> 4, b = t & 15;
        int n2 = blockIdx.x * 4 + nl2;
        float xv[DD_], h[DD_];
        #pragma unroll
        for (int j = 0; j < DD_; j++) {
            xv[j] = msg[nl2][b * DD_ + j];
            h[j] = Hin[(long)n2 * 80 + b * DD_ + j];
        }
        float gi[3 * DD_], gh[3 * DD_];
        #pragma unroll
        for (int g = 0; g < 3 * DD_; g++) {
            float a = b_ih[g], cc = b_hh[g];
            #pragma unroll
            for (int k = 0; k < DD_; k++) {
                a = fmaf(xv[k], W_ih[g * DD_ + k], a);
                cc = fmaf(h[k], W_hh[g * DD_ + k], cc);
            }
            gi[g] = a; gh[g] = cc;
        }
        #pragma unroll
        for (int j = 0; j < DD_; j++) {
            float rr = 1.f / (1.f + expf(-(gi[j] + gh[j])));
            float zz = 1.f / (1.f + expf(-(gi[DD_ + j] + gh[DD_ + j])));
            float nn2 = tanhf(gi[2 * DD_ + j] + rr * gh[2 * DD_ + j]);
            Hout[(long)n2 * 80 + b * DD_ + j] = (1.f - zz) * nn2 + zz * h[j];
        }
    }
}

__global__ void out_kernel(const float* __restrict__ ht, const float* __restrict__ Wo1,
                           const float* __restrict__ bo1, const float* __restrict__ Wo2,
                           const float* __restrict__ bo2, float* __restrict__ logits, int rows)
{
    int gid = blockIdx.x * blockDim.x + threadIdx.x;
    int wave = gid >> 6, lane = gid & 63;
    if (wave >= rows) return;
    int b = wave / N_, n = wave % N_;
    float x[DD_];
    #pragma unroll
    for (int i = 0; i < DD_; i++) x[i] = ht[(long)n * (B_ * DD_) + b * DD_ + i];
    float acc = 0.f;
    for (int j = lane; j < HD_; j += 64) {
        float h = bo1[j];
        #pragma unroll
        for (int d = 0; d < DD_; d++) h = fmaf(x[d], Wo1[d * HD_ + j], h);
        h = fmaxf(h, 0.f);
        acc = fmaf(h, Wo2[j], acc);
    }
    #pragma unroll
    for (int off = 32; off; off >>= 1) acc += __shfl_down(acc, off);
    if (lane == 0) logits[wave] = acc + bo2[0];
}

// ---------------------------------------------------------------------------
extern "C" void kernel_launch(void* const* d_in, const int* in_sizes, int n_in,
                              void* d_out, int out_size, void* d_ws, size_t ws_size,
                              hipStream_t stream)
{
    const float* feats   = (const float*)d_in[0];
    const float* embed   = (const float*)d_in[1];
    const int*   edges   = (const int*)  d_in[2];
    const float* W_key   = (const float*)d_in[3];
    const float* b_key   = (const float*)d_in[4];
    const float* W_query = (const float*)d_in[5];
    const float* b_query = (const float*)d_in[6];
    const float* Wf1     = (const float*)d_in[7];
    const float* bf1     = (const float*)d_in[8];
    const float* Wf2     = (const float*)d_in[9];
    const float* bf2     = (const float*)d_in[10];
    const float* Wr1     = (const float*)d_in[11];
    const float* br1     = (const float*)d_in[12];
    const float* Wr2     = (const float*)d_in[13];
    const float* br2     = (const float*)d_in[14];
    const float* Wo1     = (const float*)d_in[15];
    const float* bo1     = (const float*)d_in[16];
    const float* Wo2     = (const float*)d_in[17];
    const float* bo2     = (const float*)d_in[18];
    const float* W_ih    = (const float*)d_in[19];
    const float* b_ih    = (const float*)d_in[20];
    const float* W_hh    = (const float*)d_in[21];
    const float* b_hh    = (const float*)d_in[22];
    const float* W_clf   = (const float*)d_in[23];
    const float* b_clf   = (const float*)d_in[24];

    float* out_logits = (float*)d_out;
    float* out_attn   = out_logits + B_ * N_;
    float* out_img    = out_attn + (long)B_ * N_ * L_;

    char* p = (char*)d_ws;
    auto alloc = [&](size_t bytes) { void* r = (void*)p; p += (bytes + 255) & ~(size_t)255; return r; };
    float* pooled  = (float*)alloc((size_t)B_ * FD_ * 4);
    short* featsH  = (short*)alloc((size_t)B_ * L_ * FD_ * 2);
    short* featsL  = (short*)alloc((size_t)B_ * L_ * FD_ * 2);
    short* WkfH    = (short*)alloc((size_t)1024 * FD_ * 2);
    short* WkfL    = (short*)alloc((size_t)1024 * FD_ * 2);
    short* WqTh    = (short*)alloc((size_t)HD_ * WD_ * 2);
    short* WqTl    = (short*)alloc((size_t)HD_ * WD_ * 2);
    short* Wr1T    = (short*)alloc((size_t)256 * 600 * 2);
    short* embH    = (short*)alloc((size_t)N_ * WD_ * 2);
    short* embL    = (short*)alloc((size_t)N_ * WD_ * 2);
    short* keysH   = (short*)alloc((size_t)B_ * L_ * HD_ * 2);
    short* keysL   = (short*)alloc((size_t)B_ * L_ * HD_ * 2);
    short* qH      = (short*)alloc((size_t)N_ * HD_ * 2);
    short* qL      = (short*)alloc((size_t)N_ * HD_ * 2);
    short* attnH   = (short*)alloc((size_t)B_ * N_ * L_ * 2);
    short* F1T     = (short*)alloc((size_t)B_ * HD_ * L_ * 2);
    float* prop    = (float*)alloc((size_t)N_ * N_ * 4);
    float* Ht0     = (float*)alloc((size_t)N_ * B_ * DD_ * 4);
    float* Ht1     = (float*)alloc((size_t)N_ * B_ * DD_ * 4);
    float* Pimg    = (float*)alloc((size_t)8 * B_ * NIMG_ * 4);
    float* Pk      = (float*)alloc((size_t)PK_ELEMS * 4);

    // --- init accumulators (prop, Pk, out_attn, Ht0=bf2) ---
    init_all<<<(PK_ELEMS + 255) / 256, 256, 0, stream>>>(prop, Pk, out_attn, Ht0, bf2);

    // --- imagenet classifier path ---
    pooled_kernel<<<(B_ * FD_ + 255) / 256, 256, 0, stream>>>(feats, pooled);
    {
        dim3 g((B_ * NIMG_ + 255) / 256, FD_ / 256);
        clf_partial<<<g, 256, 0, stream>>>(pooled, W_clf, b_clf, Pimg);
    }
    softmax_img<<<(B_ * 64 + 255) / 256, 256, 0, stream>>>(Pimg, out_img, B_);

    // --- operand pre-conversion ---
    {
        int n4 = B_ * L_ * FD_ / 4;
        conv_split<<<(n4 + 255) / 256, 256, 0, stream>>>(feats, featsH, featsL, n4);
    }
    {
        int n4 = N_ * WD_ / 4;
        conv_split<<<(n4 + 255) / 256, 256, 0, stream>>>(embed, embH, embL, n4);
    }
    {
        dim3 g((FD_ + 31) / 32, (HD_ + 31) / 32);
        transconv<<<g, 256, 0, stream>>>(W_key, WkfH, WkfL, FD_, HD_);
        transconv<<<g, 256, 0, stream>>>(Wf1, WkfH + (size_t)512 * FD_,
                                         WkfL + (size_t)512 * FD_, FD_, HD_);
    }
    {
        dim3 g((WD_ + 31) / 32, (HD_ + 31) / 32);
        transconv<<<g, 256, 0, stream>>>(W_query, WqTh, WqTl, WD_, HD_);
    }
    {
        dim3 g((600 + 31) / 32, (256 + 31) / 32);
        transconv<<<g, 256, 0, stream>>>(Wr1, Wr1T, nullptr, 600, 256);
    }

    // --- prop matrix ---
    edge_mfma<<<(E_ + 63) / 64, 256, 0, stream>>>(embH, edges, Wr1T, br1, Wr2, br2, prop);

    // --- fused keys+F1 GEMM, split-K=2 -> Pk (atomic fp32) ---
    {
        dim3 g(1024 / 64, (B_ * L_ + 127) / 128, 2);
        mm4<OUT_PART, true><<<g, 256, 0, stream>>>(
            featsH, featsL, WkfH, WkfL, nullptr, Pk, nullptr, nullptr,
            B_ * L_, 1024, FD_, 0, 0, 0, FD_ / 2);
    }
    reduce_kf1<<<(PK_ELEMS / 4 + 255) / 256, 256, 0, stream>>>(Pk, b_key, keysH, keysL, F1T);

    // --- queries = embed @ W_query + b_query -> hi/lo planes ---
    {
        dim3 g(HD_ / 64, (N_ + 127) / 128, 1);
        mm4<OUT_SPLIT, true><<<g, 256, 0, stream>>>(
            embH, embL, WqTh, WqTl, b_query, qH, qL, nullptr, N_, HD_, WD_, 0, 0, 0, 0);
    }
    // --- scores, split-K=2, atomic into zeroed out_attn ---
    {
        dim3 g((L_ + 63) / 64, (N_ + 127) / 128, B_ * 2);
        mm4<OUT_PARTB, true><<<g, 256, 0, stream>>>(
            qH, qL, keysH, keysL, nullptr, out_attn, nullptr, nullptr, N_, L_, HD_,
            0, (long)L_ * HD_, (long)N_ * L_, HD_ / 2);
    }
    softmax_attn<<<(B_ * N_ * 64 + 255) / 256, 256, 0, stream>>>(out_attn, attnH, B_ * N_);

    // --- h1 GEMM with fused h0 epilogue (atomic into bf2-initialized Ht0) ---
    {
        dim3 g(HD_ / 64, (N_ + 127) / 128, B_);
        mm4<OUT_H0, false><<<g, 256, 0, stream>>>(
            attnH, nullptr, F1T, nullptr, bf1, Ht0, nullptr, Wf2, N_, HD_, L_,
            (long)N_ * L_, (long)HD_ * L_, 0, 0);
    }

    // --- recurrence: 5 fused steps, ping-pong ---
    {
        float* hin = Ht0;
        float* hout = Ht1;
        for (int step = 0; step < TMAX_; step++) {
            step_kernel<<<N_ / 4, 320, 0, stream>>>(prop, hin, hout,
                                                    W_ih, b_ih, W_hh, b_hh);
            float* tmp = hin; hin = hout; hout = tmp;
        }
        out_kernel<<<(B_ * N_ * 64 + 255) / 256, 256, 0, stream>>>(hin, Wo1, bo1, Wo2, bo2,
                                                                   out_logits, B_ * N_);
    }
}

// Round 9
// 588.618 us; speedup vs baseline: 1.2841x; 1.2841x over previous
//
#include <hip/hip_runtime.h>
#include <hip/hip_bf16.h>
#include <math.h>

// Problem constants
#define B_   16
#define L_   196
#define FD_  2048
#define N_   1000
#define WD_  300
#define HD_  512
#define DD_  5
#define E_   50000
#define TMAX_ 5
#define NIMG_ 1000

typedef __attribute__((ext_vector_type(8))) short bf16x8;
typedef __attribute__((ext_vector_type(4))) float f32x4;

#define SMEM_BYTES 30976

__device__ __forceinline__ short bf_hi(float x) {
    unsigned u = __float_as_uint(x);
    unsigned r = u + 0x7fffu + ((u >> 16) & 1u);
    return (short)(r >> 16);
}
__device__ __forceinline__ float bf2f_(short s) {
    return __uint_as_float(((unsigned)(unsigned short)s) << 16);
}

__device__ __forceinline__ void load8s(const short* __restrict__ rowp, bool rowok,
                                       int gk, int bound, short* tmp)
{
    if (rowok && gk + 8 <= bound) {
        *(int2*)&tmp[0] = *(const int2*)(rowp + gk);
        *(int2*)&tmp[4] = *(const int2*)(rowp + gk + 4);
    } else {
        #pragma unroll
        for (int j = 0; j < 8; j++)
            tmp[j] = (rowok && gk + j < bound) ? rowp[gk + j] : (short)0;
    }
}

// ---------------------------------------------------------------------------
// MFMA GEMM core. A,B bf16 planes [rows][K] (hi + optional lo). Block tile
// 128x64, 256 threads = 4 waves (each 32 rows x 64 cols), BK=32, 16x16x32.
// SPLIT: AhBh + AlBh + AhBl fused in-loop.
// ---------------------------------------------------------------------------
#define OUT_SPLIT 1
#define OUT_SC    2
#define OUT_KF1   3
#define OUT_H0    4

template<int OUTMODE, bool SPLIT>
__device__ __forceinline__ void mm_core(
    char* sm, int bx, int by, int zb,
    const short* __restrict__ Ah, const short* __restrict__ Al,
    const short* __restrict__ Bh, const short* __restrict__ Bl,
    const float* __restrict__ bias, void* __restrict__ C0, void* __restrict__ C1,
    void* __restrict__ C2, const float* __restrict__ W2,
    int M, int N, int K, int kbeg, int kend)
{
    short (*AsH)[40] = (short(*)[40])sm;
    short (*AsL)[40] = (short(*)[40])(sm + 10240);
    short (*BsH)[40] = (short(*)[40])(sm + 20480);
    short (*BsL)[40] = (short(*)[40])(sm + 25600);
    int t = threadIdx.x;
    int lane = t & 63, w = t >> 6;
    int q = lane >> 4, r = lane & 15;
    int row0 = by * 128, col0 = bx * 64;
    f32x4 zero4 = {0.f, 0.f, 0.f, 0.f};
    f32x4 acc[2][4];
    #pragma unroll
    for (int i = 0; i < 2; i++)
        #pragma unroll
        for (int j = 0; j < 4; j++) acc[i][j] = zero4;

    int arow = t >> 1, akc = (t & 1) * 16;
    int brow = t >> 2, bkc = (t & 3) * 8;
    for (int k0 = kbeg; k0 < kend; k0 += 32) {
        short tmp[8];
        {
            int gm = row0 + arow;
            bool ok = gm < M;
            const short* ap = Ah + (long)gm * K;
            load8s(ap, ok, k0 + akc, kend, tmp);
            *(int4*)&AsH[arow][akc] = *(int4*)tmp;
            load8s(ap, ok, k0 + akc + 8, kend, tmp);
            *(int4*)&AsH[arow][akc + 8] = *(int4*)tmp;
            if (SPLIT) {
                const short* alp = Al + (long)gm * K;
                load8s(alp, ok, k0 + akc, kend, tmp);
                *(int4*)&AsL[arow][akc] = *(int4*)tmp;
                load8s(alp, ok, k0 + akc + 8, kend, tmp);
                *(int4*)&AsL[arow][akc + 8] = *(int4*)tmp;
            }
        }
        {
            int gn = col0 + brow;
            bool ok = gn < N;
            load8s(Bh + (long)gn * K, ok, k0 + bkc, kend, tmp);
            *(int4*)&BsH[brow][bkc] = *(int4*)tmp;
            if (SPLIT) {
                load8s(Bl + (long)gn * K, ok, k0 + bkc, kend, tmp);
                *(int4*)&BsL[brow][bkc] = *(int4*)tmp;
            }
        }
        __syncthreads();
        bf16x8 ah0 = *(const bf16x8*)&AsH[w * 32 + r][q * 8];
        bf16x8 ah1 = *(const bf16x8*)&AsH[w * 32 + 16 + r][q * 8];
        bf16x8 al0, al1;
        if (SPLIT) {
            al0 = *(const bf16x8*)&AsL[w * 32 + r][q * 8];
            al1 = *(const bf16x8*)&AsL[w * 32 + 16 + r][q * 8];
        }
        #pragma unroll
        for (int ct = 0; ct < 4; ct++) {
            bf16x8 bh = *(const bf16x8*)&BsH[ct * 16 + r][q * 8];
            acc[0][ct] = __builtin_amdgcn_mfma_f32_16x16x32_bf16(ah0, bh, acc[0][ct], 0, 0, 0);
            acc[1][ct] = __builtin_amdgcn_mfma_f32_16x16x32_bf16(ah1, bh, acc[1][ct], 0, 0, 0);
            if (SPLIT) {
                acc[0][ct] = __builtin_amdgcn_mfma_f32_16x16x32_bf16(al0, bh, acc[0][ct], 0, 0, 0);
                acc[1][ct] = __builtin_amdgcn_mfma_f32_16x16x32_bf16(al1, bh, acc[1][ct], 0, 0, 0);
                bf16x8 bl = *(const bf16x8*)&BsL[ct * 16 + r][q * 8];
                acc[0][ct] = __builtin_amdgcn_mfma_f32_16x16x32_bf16(ah0, bl, acc[0][ct], 0, 0, 0);
                acc[1][ct] = __builtin_amdgcn_mfma_f32_16x16x32_bf16(ah1, bl, acc[1][ct], 0, 0, 0);
            }
        }
        __syncthreads();
    }

    if (OUTMODE == OUT_H0) {
        // relu(v + bias[n]) * W2[n][d], reduce over 64 n-cols, atomicAdd into
        // C0 = Ht0 [node][16][5] at batch zb
        float s[2][4][DD_];
        #pragma unroll
        for (int i = 0; i < 2; i++)
            #pragma unroll
            for (int reg = 0; reg < 4; reg++)
                #pragma unroll
                for (int d = 0; d < DD_; d++) s[i][reg][d] = 0.f;
        #pragma unroll
        for (int i = 0; i < 2; i++) {
            #pragma unroll
            for (int ct = 0; ct < 4; ct++) {
                int n = col0 + ct * 16 + r;
                float w2v[DD_];
                #pragma unroll
                for (int d = 0; d < DD_; d++) w2v[d] = W2[n * DD_ + d];
                float b1 = bias[n];
                #pragma unroll
                for (int reg = 0; reg < 4; reg++) {
                    int m = row0 + w * 32 + i * 16 + q * 4 + reg;
                    if (m >= M) continue;
                    float val = fmaxf(acc[i][ct][reg] + b1, 0.f);
                    #pragma unroll
                    for (int d = 0; d < DD_; d++) s[i][reg][d] = fmaf(val, w2v[d], s[i][reg][d]);
                }
            }
        }
        #pragma unroll
        for (int i = 0; i < 2; i++)
            #pragma unroll
            for (int reg = 0; reg < 4; reg++)
                #pragma unroll
                for (int d = 0; d < DD_; d++) {
                    float v = s[i][reg][d];
                    v += __shfl_xor(v, 1);
                    v += __shfl_xor(v, 2);
                    v += __shfl_xor(v, 4);
                    v += __shfl_xor(v, 8);
                    if (r == 0) {
                        int m = row0 + w * 32 + i * 16 + q * 4 + reg;
                        if (m < M)
                            atomicAdd(&((float*)C0)[(long)m * (B_ * DD_) + zb * DD_ + d], v);
                    }
                }
        return;
    }

    #pragma unroll
    for (int i = 0; i < 2; i++) {
        #pragma unroll
        for (int ct = 0; ct < 4; ct++) {
            #pragma unroll
            for (int reg = 0; reg < 4; reg++) {
                int m = row0 + w * 32 + i * 16 + q * 4 + reg;
                int n = col0 + ct * 16 + r;
                if (m >= M || n >= N) continue;
                float v = acc[i][ct][reg];
                if (OUTMODE == OUT_KF1) {
                    if (col0 < 512) {  // keys half (block-uniform)
                        float v2 = v + bias[n];
                        long idx = (long)m * 512 + n;
                        short hi = bf_hi(v2);
                        ((short*)C0)[idx] = hi;
                        ((short*)C1)[idx] = bf_hi(v2 - bf2f_(hi));
                    } else {           // F1 half -> F1^T bf16 [b][512][196]
                        int b = m / 196, l = m - b * 196;
                        int nf = n - 512;
                        ((short*)C2)[((long)b * 512 + nf) * 196 + l] = bf_hi(v);
                    }
                } else if (OUTMODE == OUT_SC) {
                    ((float*)C0)[(long)m * N + n] = v;
                } else { // OUT_SPLIT
                    float v2 = v + bias[n];
                    long idx = (long)m * N + n;
                    short hi = bf_hi(v2);
                    ((short*)C0)[idx] = hi;
                    ((short*)C1)[idx] = bf_hi(v2 - bf2f_(hi));
                }
            }
        }
    }
}

// ---------------------------------------------------------------------------
// Edge MLP core: 64 edges x 256 units/block, K=600.
// ---------------------------------------------------------------------------
__device__ __forceinline__ void edge_core(
    char* sm, int be,
    const short* __restrict__ embedH, const int* __restrict__ edges,
    const short* __restrict__ Wr1T, const float* __restrict__ br1,
    const float* __restrict__ Wr2, const float* __restrict__ br2,
    float* __restrict__ prop)
{
    short (*As)[40] = (short(*)[40])sm;
    short (*Bs)[40] = (short(*)[40])(sm + 5120);
    int* src = (int*)(sm + 25600);
    int* dst = (int*)(sm + 25856);
    float (*part)[5] = (float(*)[5])(sm + 26112);
    int t = threadIdx.x;
    int e0 = be * 64;
    if (t < 64) {
        int e = e0 + t;
        src[t] = (e < E_) ? edges[e] : 0;
        dst[t] = (e < E_) ? edges[E_ + e] : 0;
    }
    __syncthreads();
    int lane = t & 63, w = t >> 6, q = lane >> 4, r = lane & 15;
    f32x4 zero4 = {0.f, 0.f, 0.f, 0.f};
    f32x4 acc[4][4];
    #pragma unroll
    for (int i = 0; i < 4; i++)
        #pragma unroll
        for (int j = 0; j < 4; j++) acc[i][j] = zero4;

    for (int ks = 0; ks < 19; ks++) {
        int k0 = ks * 32;
        {
            int arow = t >> 2, kc = (t & 3) * 8;
            int gk0 = k0 + kc;
            int sn = src[arow], dn = dst[arow];
            short tmp[8];
            if (gk0 + 8 <= 300) {
                const short* p = embedH + (long)sn * 300 + gk0;
                *(int2*)&tmp[0] = *(const int2*)p;
                *(int2*)&tmp[4] = *(const int2*)(p + 4);
            } else if (gk0 >= 300 && gk0 + 8 <= 600) {
                const short* p = embedH + (long)dn * 300 + (gk0 - 300);
                *(int2*)&tmp[0] = *(const int2*)p;
                *(int2*)&tmp[4] = *(const int2*)(p + 4);
            } else {
                #pragma unroll
                for (int j = 0; j < 8; j++) {
                    int gk = gk0 + j;
                    short v = 0;
                    if (gk < 300) v = embedH[(long)sn * 300 + gk];
                    else if (gk < 600) v = embedH[(long)dn * 300 + gk - 300];
                    tmp[j] = v;
                }
            }
            *(int4*)&As[arow][kc] = *(int4*)&tmp[0];
        }
        #pragma unroll
        for (int i = 0; i < 4; i++) {
            int n = i * 64 + (t >> 2), kc = (t & 3) * 8;
            int gk0 = k0 + kc;
            short tmp[8];
            if (gk0 + 8 <= 600) {
                const short* p = Wr1T + (long)n * 600 + gk0;
                *(int2*)&tmp[0] = *(const int2*)p;
                *(int2*)&tmp[4] = *(const int2*)(p + 4);
            } else {
                #pragma unroll
                for (int j = 0; j < 8; j++) tmp[j] = 0;
            }
            *(int4*)&Bs[n][kc] = *(int4*)&tmp[0];
        }
        __syncthreads();
        bf16x8 af[4], bfr[4];
        #pragma unroll
        for (int rt = 0; rt < 4; rt++) af[rt] = *(const bf16x8*)&As[rt * 16 + r][q * 8];
        #pragma unroll
        for (int ct = 0; ct < 4; ct++) bfr[ct] = *(const bf16x8*)&Bs[w * 64 + ct * 16 + r][q * 8];
        #pragma unroll
        for (int rt = 0; rt < 4; rt++)
            #pragma unroll
            for (int ct = 0; ct < 4; ct++)
                acc[rt][ct] = __builtin_amdgcn_mfma_f32_16x16x32_bf16(af[rt], bfr[ct], acc[rt][ct], 0, 0, 0);
        __syncthreads();
    }
    float b1v[4], w2v[4];
    #pragma unroll
    for (int ct = 0; ct < 4; ct++) {
        int u = w * 64 + ct * 16 + r;
        b1v[ct] = br1[u];
        w2v[ct] = Wr2[u];
    }
    #pragma unroll
    for (int rt = 0; rt < 4; rt++) {
        #pragma unroll
        for (int reg = 0; reg < 4; reg++) {
            float s = 0.f;
            #pragma unroll
            for (int ct = 0; ct < 4; ct++)
                s = fmaf(fmaxf(acc[rt][ct][reg] + b1v[ct], 0.f), w2v[ct], s);
            s += __shfl_xor(s, 1);
            s += __shfl_xor(s, 2);
            s += __shfl_xor(s, 4);
            s += __shfl_xor(s, 8);
            if (r == 0) part[rt * 16 + q * 4 + reg][w] = s;
        }
    }
    __syncthreads();
    if (t < 64 && e0 + t < E_) {
        float s = part[t][0] + part[t][1] + part[t][2] + part[t][3];
        atomicAdd(&prop[(long)src[t] * N_ + dst[t]], tanhf(s + br2[0]));
    }
}

// ---------------------------------------------------------------------------
// transpose+convert core: in fp32 [K][N] -> outH/outL bf16 [N][K], 32x32 tile
// ---------------------------------------------------------------------------
__device__ __forceinline__ void transconv_core(
    char* sm, int bx, int by,
    const float* __restrict__ in, short* __restrict__ outH, short* __restrict__ outL,
    int K, int N)
{
    float (*tile)[33] = (float(*)[33])sm;
    int k0 = bx * 32, n0 = by * 32;
    int t = threadIdx.x;
    int tr = t >> 5, tc = t & 31;
    #pragma unroll
    for (int i = 0; i < 4; i++) {
        int k = k0 + tr + i * 8, n = n0 + tc;
        tile[tr + i * 8][tc] = (k < K && n < N) ? in[(long)k * N + n] : 0.f;
    }
    __syncthreads();
    #pragma unroll
    for (int i = 0; i < 4; i++) {
        int n = n0 + tr + i * 8, k = k0 + tc;
        if (n < N && k < K) {
            float x = tile[tc][tr + i * 8];
            short hi = bf_hi(x);
            outH[(long)n * K + k] = hi;
            if (outL) outL[(long)n * K + k] = bf_hi(x - bf2f_(hi));
        }
    }
}

// ---------------------------------------------------------------------------
// K0: all prep in one launch (zero/init, pooled, conversions, transposes)
// block ranges: [0,977) prop zero | [977,1290) Ht0=bf2 | [1290,1418) pooled |
// [1418,4554) feats conv8 | [4554,4847) embed conv4 | [4847,5871) W_key T |
// [5871,6895) Wf1 T | [6895,7055) W_query T | [7055,7207) Wr1 T
// ---------------------------------------------------------------------------
__global__ __launch_bounds__(256) void prep(
    float* __restrict__ prop, float* __restrict__ Ht0, const float* __restrict__ bf2,
    const float* __restrict__ feats, float* __restrict__ pooled,
    short* __restrict__ featsH, short* __restrict__ featsL,
    const float* __restrict__ embed, short* __restrict__ embH, short* __restrict__ embL,
    const float* __restrict__ W_key, const float* __restrict__ Wf1,
    short* __restrict__ WkfH, short* __restrict__ WkfL,
    const float* __restrict__ W_query, short* __restrict__ WqTh, short* __restrict__ WqTl,
    const float* __restrict__ Wr1, short* __restrict__ Wr1T)
{
    __shared__ __align__(16) char sm[SMEM_BYTES];
    int b = blockIdx.x, t = threadIdx.x;
    if (b < 977) {
        int i = (b * 256 + t) * 4;
        if (i < N_ * N_) { float4 z = {0.f, 0.f, 0.f, 0.f}; *(float4*)(prop + i) = z; }
    } else if (b < 1290) {
        int i = (b - 977) * 256 + t;
        if (i < N_ * B_ * DD_) Ht0[i] = bf2[i % DD_];
    } else if (b < 1418) {
        int idx = (b - 1290) * 256 + t;
        int bb = idx / FD_, f = idx % FD_;
        const float* p = feats + (long)bb * L_ * FD_ + f;
        float acc = 0.f;
        for (int l = 0; l < L_; l++) acc += p[(long)l * FD_];
        pooled[idx] = acc * (1.0f / L_);
    } else if (b < 4554) {
        long i = ((long)(b - 1418) * 256 + t) * 8;
        float4 v0 = *(const float4*)(feats + i);
        float4 v1 = *(const float4*)(feats + i + 4);
        float xs[8] = {v0.x, v0.y, v0.z, v0.w, v1.x, v1.y, v1.z, v1.w};
        short h[8], l8[8];
        #pragma unroll
        for (int j = 0; j < 8; j++) {
            h[j] = bf_hi(xs[j]);
            l8[j] = bf_hi(xs[j] - bf2f_(h[j]));
        }
        *(int4*)(featsH + i) = *(int4*)h;
        *(int4*)(featsL + i) = *(int4*)l8;
    } else if (b < 4847) {
        int i = ((b - 4554) * 256 + t) * 4;
        if (i < N_ * WD_) {
            float4 v = *(const float4*)(embed + i);
            float xs[4] = {v.x, v.y, v.z, v.w};
            short h[4], l4[4];
            #pragma unroll
            for (int j = 0; j < 4; j++) {
                h[j] = bf_hi(xs[j]);
                l4[j] = bf_hi(xs[j] - bf2f_(h[j]));
            }
            *(int2*)(embH + i) = *(int2*)h;
            *(int2*)(embL + i) = *(int2*)l4;
        }
    } else if (b < 5871) {
        int bb = b - 4847;
        transconv_core(sm, bb % 64, bb / 64, W_key, WkfH, WkfL, FD_, HD_);
    } else if (b < 6895) {
        int bb = b - 5871;
        transconv_core(sm, bb % 64, bb / 64, Wf1,
                       WkfH + (size_t)512 * FD_, WkfL + (size_t)512 * FD_, FD_, HD_);
    } else if (b < 7055) {
        int bb = b - 6895;
        transconv_core(sm, bb % 10, bb / 10, W_query, WqTh, WqTl, WD_, HD_);
    } else {
        int bb = b - 7055;
        transconv_core(sm, bb % 19, bb / 19, Wr1, Wr1T, nullptr, 600, 256);
    }
}

// ---------------------------------------------------------------------------
// K1: mega compute — kf1 GEMM (400) + queries GEMM (64) + edge (782) + clf (504)
// ---------------------------------------------------------------------------
__global__ __launch_bounds__(256) void mega1(
    const short* __restrict__ featsH, const short* __restrict__ featsL,
    const short* __restrict__ WkfH, const short* __restrict__ WkfL,
    const float* __restrict__ b_key, short* __restrict__ keysH, short* __restrict__ keysL,
    short* __restrict__ F1T,
    const short* __restrict__ embH, const short* __restrict__ embL,
    const short* __restrict__ WqTh, const short* __restrict__ WqTl,
    const float* __restrict__ b_query, short* __restrict__ qH, short* __restrict__ qL,
    const int* __restrict__ edges, const short* __restrict__ Wr1T,
    const float* __restrict__ br1, const float* __restrict__ Wr2,
    const float* __restrict__ br2, float* __restrict__ prop,
    const float* __restrict__ pooled, const float* __restrict__ W_clf,
    const float* __restrict__ b_clf, float* __restrict__ Pimg)
{
    __shared__ __align__(16) char sm[SMEM_BYTES];
    int b = blockIdx.x;
    if (b < 400) {
        mm_core<OUT_KF1, true>(sm, b & 15, b >> 4, 0, featsH, featsL, WkfH, WkfL,
                               b_key, keysH, keysL, F1T, nullptr,
                               B_ * L_, 1024, FD_, 0, FD_);
    } else if (b < 464) {
        int bb = b - 400;
        mm_core<OUT_SPLIT, true>(sm, bb & 7, bb >> 3, 0, embH, embL, WqTh, WqTl,
                                 b_query, qH, qL, nullptr, nullptr,
                                 N_, HD_, WD_, 0, WD_);
    } else if (b < 1246) {
        edge_core(sm, b - 464, embH, edges, Wr1T, br1, Wr2, br2, prop);
    } else {
        int bb = b - 1246;
        int ks = bb / 63, ix = bb % 63;
        int i = ix * 256 + threadIdx.x;
        if (i < B_ * NIMG_) {
            int bi = i / NIMG_, n = i % NIMG_;
            const float* p = pooled + (long)bi * FD_ + ks * 256;
            const float* w = W_clf + (long)(ks * 256) * NIMG_ + n;
            float acc = (ks == 0) ? b_clf[n] : 0.f;
            #pragma unroll 4
            for (int k = 0; k < 256; k++) acc = fmaf(p[k], w[(long)k * NIMG_], acc);
            Pimg[(long)ks * (B_ * NIMG_) + i] = acc;
        }
    }
}

// ---------------------------------------------------------------------------
// K2: scores GEMM into 2 k-chunk planes (1024) + softmax_img (4)
// ---------------------------------------------------------------------------
__global__ __launch_bounds__(256) void mega2(
    const short* __restrict__ qH, const short* __restrict__ qL,
    const short* __restrict__ keysH, const short* __restrict__ keysL,
    float* __restrict__ Pattn,
    const float* __restrict__ Pimg, float* __restrict__ out_img)
{
    __shared__ __align__(16) char sm[SMEM_BYTES];
    int b = blockIdx.x;
    if (b < 1024) {
        int bx = b & 3, by = (b >> 2) & 7, zb = (b >> 5) & 15, kc = b >> 9;
        const short* Bh = keysH + (long)zb * L_ * HD_;
        const short* Bl = keysL + (long)zb * L_ * HD_;
        float* C0 = Pattn + (long)kc * ((long)B_ * N_ * L_) + (long)zb * N_ * L_;
        mm_core<OUT_SC, true>(sm, bx, by, 0, qH, qL, Bh, Bl, nullptr,
                              C0, nullptr, nullptr, nullptr,
                              N_, L_, HD_, kc * 256, kc * 256 + 256);
    } else {
        int t = threadIdx.x;
        int wave = (b - 1024) * 4 + (t >> 6), lane = t & 63;
        if (wave >= B_) return;
        const int PER = (NIMG_ + 63) / 64;
        float v[PER];
        float m = -1e30f;
        int cnt = 0;
        for (int k = lane; k < NIMG_; k += 64) {
            float s = 0.f;
            #pragma unroll
            for (int ks = 0; ks < 8; ks++) s += Pimg[(long)ks * (B_ * NIMG_) + wave * NIMG_ + k];
            v[cnt] = s; m = fmaxf(m, s); cnt++;
        }
        #pragma unroll
        for (int off = 32; off; off >>= 1) m = fmaxf(m, __shfl_xor(m, off));
        float s = 0.f;
        for (int i = 0; i < cnt; i++) { v[i] = expf(v[i] - m); s += v[i]; }
        #pragma unroll
        for (int off = 32; off; off >>= 1) s += __shfl_xor(s, off);
        float inv = 1.f / s;
        cnt = 0;
        for (int k = lane; k < NIMG_; k += 64) out_img[(long)wave * NIMG_ + k] = v[cnt++] * inv;
    }
}

// ---------------------------------------------------------------------------
// softmax over 196 of (P0+P1); writes out_attn fp32 + attnH bf16
// ---------------------------------------------------------------------------
__global__ void softmax_attn(const float* __restrict__ P0, const float* __restrict__ P1,
                             float* __restrict__ X, short* __restrict__ Xb, int rows)
{
    int gid = blockIdx.x * blockDim.x + threadIdx.x;
    int wave = gid >> 6, lane = gid & 63;
    if (wave >= rows) return;
    const int PER = (L_ + 63) / 64;
    float v[PER];
    float m = -1e30f;
    int cnt = 0;
    for (int k = lane; k < L_; k += 64) {
        long idx = (long)wave * L_ + k;
        v[cnt] = P0[idx] + P1[idx];
        m = fmaxf(m, v[cnt]); cnt++;
    }
    #pragma unroll
    for (int off = 32; off; off >>= 1) m = fmaxf(m, __shfl_xor(m, off));
    float s = 0.f;
    for (int i = 0; i < cnt; i++) { v[i] = expf(v[i] - m); s += v[i]; }
    #pragma unroll
    for (int off = 32; off; off >>= 1) s += __shfl_xor(s, off);
    float inv = 1.f / s;
    cnt = 0;
    for (int k = lane; k < L_; k += 64) {
        float val = v[cnt++] * inv;
        long idx = (long)wave * L_ + k;
        X[idx] = val;
        Xb[idx] = bf_hi(val);
    }
}

// ---------------------------------------------------------------------------
// K4: h1 GEMM with fused h0 epilogue (atomic into bf2-initialized Ht0)
// ---------------------------------------------------------------------------
__global__ __launch_bounds__(256) void h0gemm(
    const short* __restrict__ attnH, const short* __restrict__ F1T,
    const float* __restrict__ bf1, const float* __restrict__ Wf2,
    float* __restrict__ Ht0)
{
    __shared__ __align__(16) char sm[SMEM_BYTES];
    int b = blockIdx.x;
    int bx = b & 7, by = (b >> 3) & 7, zb = b >> 6;
    const short* Ap = attnH + (long)zb * N_ * L_;
    const short* Bp = F1T + (long)zb * HD_ * L_;
    mm_core<OUT_H0, false>(sm, bx, by, zb, Ap, nullptr, Bp, nullptr,
                           bf1, Ht0, nullptr, nullptr, Wf2,
                           N_, HD_, L_, 0, L_);
}

// ---------------------------------------------------------------------------
// Recurrence step, one thread per output element (H [N][B*D=80]).
// ---------------------------------------------------------------------------
__global__ __launch_bounds__(320) void step_kernel(
    const float* __restrict__ prop, const float* __restrict__ Hin,
    float* __restrict__ Hout,
    const float* __restrict__ W_ih, const float* __restrict__ b_ih,
    const float* __restrict__ W_hh, const float* __restrict__ b_hh)
{
    __shared__ float msg[4][80];
    int t = threadIdx.x;
    int nl = t / 80, c = t - nl * 80;
    int n = blockIdx.x * 4 + nl;
    const float* pr = prop + (long)n * N_;
    const float* hc = Hin + c;
    float acc = 0.f;
    #pragma unroll 4
    for (int m4 = 0; m4 < N_; m4 += 4) {
        float4 pv = *(const float4*)(pr + m4);
        acc = fmaf(pv.x, hc[(long)(m4 + 0) * 80], acc);
        acc = fmaf(pv.y, hc[(long)(m4 + 1) * 80], acc);
        acc = fmaf(pv.z, hc[(long)(m4 + 2) * 80], acc);
        acc = fmaf(pv.w, hc[(long)(m4 + 3) * 80], acc);
    }
    msg[nl][c] = tanhf(acc);
    __syncthreads();
    if (t < 64) {
        int nl2 = t >> 4, b = t & 15;
        int n2 = blockIdx.x * 4 + nl2;
        float xv[DD_], h[DD_];
        #pragma unroll
        for (int j = 0; j < DD_; j++) {
            xv[j] = msg[nl2][b * DD_ + j];
            h[j] = Hin[(long)n2 * 80 + b * DD_ + j];
        }
        float gi[3 * DD_], gh[3 * DD_];
        #pragma unroll
        for (int g = 0; g < 3 * DD_; g++) {
            float a = b_ih[g], cc = b_hh[g];
            #pragma unroll
            for (int k = 0; k < DD_; k++) {
                a = fmaf(xv[k], W_ih[g * DD_ + k], a);
                cc = fmaf(h[k], W_hh[g * DD_ + k], cc);
            }
            gi[g] = a; gh[g] = cc;
        }
        #pragma unroll
        for (int j = 0; j < DD_; j++) {
            float rr = 1.f / (1.f + expf(-(gi[j] + gh[j])));
            float zz = 1.f / (1.f + expf(-(gi[DD_ + j] + gh[DD_ + j])));
            float nn2 = tanhf(gi[2 * DD_ + j] + rr * gh[2 * DD_ + j]);
            Hout[(long)n2 * 80 + b * DD_ + j] = (1.f - zz) * nn2 + zz * h[j];
        }
    }
}

__global__ void out_kernel(const float* __restrict__ ht, const float* __restrict__ Wo1,
                           const float* __restrict__ bo1, const float* __restrict__ Wo2,
                           const float* __restrict__ bo2, float* __restrict__ logits, int rows)
{
    int gid = blockIdx.x * blockDim.x + threadIdx.x;
    int wave = gid >> 6, lane = gid & 63;
    if (wave >= rows) return;
    int b = wave / N_, n = wave % N_;
    float x[DD_];
    #pragma unroll
    for (int i = 0; i < DD_; i++) x[i] = ht[(long)n * (B_ * DD_) + b * DD_ + i];
    float acc = 0.f;
    for (int j = lane; j < HD_; j += 64) {
        float h = bo1[j];
        #pragma unroll
        for (int d = 0; d < DD_; d++) h = fmaf(x[d], Wo1[d * HD_ + j], h);
        h = fmaxf(h, 0.f);
        acc = fmaf(h, Wo2[j], acc);
    }
    #pragma unroll
    for (int off = 32; off; off >>= 1) acc += __shfl_down(acc, off);
    if (lane == 0) logits[wave] = acc + bo2[0];
}

// ---------------------------------------------------------------------------
extern "C" void kernel_launch(void* const* d_in, const int* in_sizes, int n_in,
                              void* d_out, int out_size, void* d_ws, size_t ws_size,
                              hipStream_t stream)
{
    const float* feats   = (const float*)d_in[0];
    const float* embed   = (const float*)d_in[1];
    const int*   edges   = (const int*)  d_in[2];
    const float* W_key   = (const float*)d_in[3];
    const float* b_key   = (const float*)d_in[4];
    const float* W_query = (const float*)d_in[5];
    const float* b_query = (const float*)d_in[6];
    const float* Wf1     = (const float*)d_in[7];
    const float* bf1     = (const float*)d_in[8];
    const float* Wf2     = (const float*)d_in[9];
    const float* bf2     = (const float*)d_in[10];
    const float* Wr1     = (const float*)d_in[11];
    const float* br1     = (const float*)d_in[12];
    const float* Wr2     = (const float*)d_in[13];
    const float* br2     = (const float*)d_in[14];
    const float* Wo1     = (const float*)d_in[15];
    const float* bo1     = (const float*)d_in[16];
    const float* Wo2     = (const float*)d_in[17];
    const float* bo2     = (const float*)d_in[18];
    const float* W_ih    = (const float*)d_in[19];
    const float* b_ih    = (const float*)d_in[20];
    const float* W_hh    = (const float*)d_in[21];
    const float* b_hh    = (const float*)d_in[22];
    const float* W_clf   = (const float*)d_in[23];
    const float* b_clf   = (const float*)d_in[24];

    float* out_logits = (float*)d_out;
    float* out_attn   = out_logits + B_ * N_;
    float* out_img    = out_attn + (long)B_ * N_ * L_;

    char* p = (char*)d_ws;
    auto alloc = [&](size_t bytes) { void* r = (void*)p; p += (bytes + 255) & ~(size_t)255; return r; };
    float* pooled  = (float*)alloc((size_t)B_ * FD_ * 4);
    short* featsH  = (short*)alloc((size_t)B_ * L_ * FD_ * 2);
    short* featsL  = (short*)alloc((size_t)B_ * L_ * FD_ * 2);
    short* WkfH    = (short*)alloc((size_t)1024 * FD_ * 2);
    short* WkfL    = (short*)alloc((size_t)1024 * FD_ * 2);
    short* WqTh    = (short*)alloc((size_t)HD_ * WD_ * 2);
    short* WqTl    = (short*)alloc((size_t)HD_ * WD_ * 2);
    short* Wr1T    = (short*)alloc((size_t)256 * 600 * 2);
    short* embH    = (short*)alloc((size_t)N_ * WD_ * 2);
    short* embL    = (short*)alloc((size_t)N_ * WD_ * 2);
    short* keysH   = (short*)alloc((size_t)B_ * L_ * HD_ * 2);
    short* keysL   = (short*)alloc((size_t)B_ * L_ * HD_ * 2);
    short* qH      = (short*)alloc((size_t)N_ * HD_ * 2);
    short* qL      = (short*)alloc((size_t)N_ * HD_ * 2);
    short* attnH   = (short*)alloc((size_t)B_ * N_ * L_ * 2);
    short* F1T     = (short*)alloc((size_t)B_ * HD_ * L_ * 2);
    float* prop    = (float*)alloc((size_t)N_ * N_ * 4);
    float* Ht0     = (float*)alloc((size_t)N_ * B_ * DD_ * 4);
    float* Ht1     = (float*)alloc((size_t)N_ * B_ * DD_ * 4);
    float* Pimg    = (float*)alloc((size_t)8 * B_ * NIMG_ * 4);
    float* Pattn   = (float*)alloc((size_t)2 * B_ * N_ * L_ * 4);

    // K0: all prep
    prep<<<7207, 256, 0, stream>>>(prop, Ht0, bf2, feats, pooled, featsH, featsL,
                                   embed, embH, embL, W_key, Wf1, WkfH, WkfL,
                                   W_query, WqTh, WqTl, Wr1, Wr1T);

    // K1: kf1 + queries + edge + clf
    mega1<<<1750, 256, 0, stream>>>(featsH, featsL, WkfH, WkfL, b_key, keysH, keysL, F1T,
                                    embH, embL, WqTh, WqTl, b_query, qH, qL,
                                    edges, Wr1T, br1, Wr2, br2, prop,
                                    pooled, W_clf, b_clf, Pimg);

    // K2: scores (2 k-planes) + softmax_img
    mega2<<<1028, 256, 0, stream>>>(qH, qL, keysH, keysL, Pattn, Pimg, out_img);

    // K3: softmax over 196 (sums planes), writes out_attn + attnH
    softmax_attn<<<(B_ * N_ * 64 + 255) / 256, 256, 0, stream>>>(
        Pattn, Pattn + (long)B_ * N_ * L_, out_attn, attnH, B_ * N_);

    // K4: h1 GEMM with fused h0 epilogue
    h0gemm<<<1024, 256, 0, stream>>>(attnH, F1T, bf1, Wf2, Ht0);

    // K5..K9: recurrence
    {
        float* hin = Ht0;
        float* hout = Ht1;
        for (int step = 0; step < TMAX_; step++) {
            step_kernel<<<N_ / 4, 320, 0, stream>>>(prop, hin, hout,
                                                    W_ih, b_ih, W_hh, b_hh);
            float* tmp = hin; hin = hout; hout = tmp;
        }
        out_kernel<<<(B_ * N_ * 64 + 255) / 256, 256, 0, stream>>>(hin, Wo1, bo1, Wo2, bo2,
                                                                   out_logits, B_ * N_);
    }
}

// Round 11
// 576.616 us; speedup vs baseline: 1.3109x; 1.0208x over previous
//
#include <hip/hip_runtime.h>
#include <hip/hip_bf16.h>
#include <math.h>

// Problem constants
#define B_   16
#define L_   196
#define FD_  2048
#define N_   1000
#define WD_  300
#define HD_  512
#define DD_  5
#define E_   50000
#define TMAX_ 5
#define NIMG_ 1000

typedef __attribute__((ext_vector_type(8))) short bf16x8;
typedef __attribute__((ext_vector_type(4))) float f32x4;

#define SMEM_BYTES 30976

__device__ __forceinline__ short bf_hi(float x) {
    unsigned u = __float_as_uint(x);
    unsigned r = u + 0x7fffu + ((u >> 16) & 1u);
    return (short)(r >> 16);
}
__device__ __forceinline__ float bf2f_(short s) {
    return __uint_as_float(((unsigned)(unsigned short)s) << 16);
}

__device__ __forceinline__ void load8s(const short* __restrict__ rowp, bool rowok,
                                       int gk, int bound, short* tmp)
{
    if (rowok && gk + 8 <= bound) {
        *(int2*)&tmp[0] = *(const int2*)(rowp + gk);
        *(int2*)&tmp[4] = *(const int2*)(rowp + gk + 4);
    } else {
        #pragma unroll
        for (int j = 0; j < 8; j++)
            tmp[j] = (rowok && gk + j < bound) ? rowp[gk + j] : (short)0;
    }
}

// ---------------------------------------------------------------------------
// MFMA GEMM core. A,B bf16 planes [rows][K] (hi + optional lo). Block tile
// 128x64, 256 threads = 4 waves (each 32 rows x 64 cols), BK=32, 16x16x32.
// Staging: 4 threads/row, one 16B LDS write each (2-way banks only).
// ---------------------------------------------------------------------------
#define OUT_SPLIT 1
#define OUT_SC    2
#define OUT_F1T   3
#define OUT_H0    4

template<int OUTMODE, bool SPLIT>
__device__ __forceinline__ void mm_core(
    char* sm, int bx, int by, int zb,
    const short* __restrict__ Ah, const short* __restrict__ Al,
    const short* __restrict__ Bh, const short* __restrict__ Bl,
    const float* __restrict__ bias, void* __restrict__ C0, void* __restrict__ C1,
    void* __restrict__ C2, const float* __restrict__ W2,
    int M, int N, int K, int kbeg, int kend)
{
    short (*AsH)[40] = (short(*)[40])sm;
    short (*AsL)[40] = (short(*)[40])(sm + 10240);
    short (*BsH)[40] = (short(*)[40])(sm + 20480);
    short (*BsL)[40] = (short(*)[40])(sm + 25600);
    int t = threadIdx.x;
    int lane = t & 63, w = t >> 6;
    int q = lane >> 4, r = lane & 15;
    int row0 = by * 128, col0 = bx * 64;
    f32x4 zero4 = {0.f, 0.f, 0.f, 0.f};
    f32x4 acc[2][4];
    #pragma unroll
    for (int i = 0; i < 2; i++)
        #pragma unroll
        for (int j = 0; j < 4; j++) acc[i][j] = zero4;

    int srow = t >> 2, skc = (t & 3) * 8;   // 4 threads/row
    for (int k0 = kbeg; k0 < kend; k0 += 32) {
        short tmp[8];
        #pragma unroll
        for (int pass = 0; pass < 2; pass++) {
            int row = pass * 64 + srow;
            int gm = row0 + row;
            bool ok = gm < M;
            load8s(Ah + (long)gm * K, ok, k0 + skc, kend, tmp);
            *(int4*)&AsH[row][skc] = *(int4*)tmp;
            if (SPLIT) {
                load8s(Al + (long)gm * K, ok, k0 + skc, kend, tmp);
                *(int4*)&AsL[row][skc] = *(int4*)tmp;
            }
        }
        {
            int gn = col0 + srow;
            bool ok = gn < N;
            load8s(Bh + (long)gn * K, ok, k0 + skc, kend, tmp);
            *(int4*)&BsH[srow][skc] = *(int4*)tmp;
            if (SPLIT) {
                load8s(Bl + (long)gn * K, ok, k0 + skc, kend, tmp);
                *(int4*)&BsL[srow][skc] = *(int4*)tmp;
            }
        }
        __syncthreads();
        bf16x8 ah0 = *(const bf16x8*)&AsH[w * 32 + r][q * 8];
        bf16x8 ah1 = *(const bf16x8*)&AsH[w * 32 + 16 + r][q * 8];
        bf16x8 al0, al1;
        if (SPLIT) {
            al0 = *(const bf16x8*)&AsL[w * 32 + r][q * 8];
            al1 = *(const bf16x8*)&AsL[w * 32 + 16 + r][q * 8];
        }
        #pragma unroll
        for (int ct = 0; ct < 4; ct++) {
            bf16x8 bh = *(const bf16x8*)&BsH[ct * 16 + r][q * 8];
            acc[0][ct] = __builtin_amdgcn_mfma_f32_16x16x32_bf16(ah0, bh, acc[0][ct], 0, 0, 0);
            acc[1][ct] = __builtin_amdgcn_mfma_f32_16x16x32_bf16(ah1, bh, acc[1][ct], 0, 0, 0);
            if (SPLIT) {
                acc[0][ct] = __builtin_amdgcn_mfma_f32_16x16x32_bf16(al0, bh, acc[0][ct], 0, 0, 0);
                acc[1][ct] = __builtin_amdgcn_mfma_f32_16x16x32_bf16(al1, bh, acc[1][ct], 0, 0, 0);
                bf16x8 bl = *(const bf16x8*)&BsL[ct * 16 + r][q * 8];
                acc[0][ct] = __builtin_amdgcn_mfma_f32_16x16x32_bf16(ah0, bl, acc[0][ct], 0, 0, 0);
                acc[1][ct] = __builtin_amdgcn_mfma_f32_16x16x32_bf16(ah1, bl, acc[1][ct], 0, 0, 0);
            }
        }
        __syncthreads();
    }

    if (OUTMODE == OUT_H0) {
        float s[2][4][DD_];
        #pragma unroll
        for (int i = 0; i < 2; i++)
            #pragma unroll
            for (int reg = 0; reg < 4; reg++)
                #pragma unroll
                for (int d = 0; d < DD_; d++) s[i][reg][d] = 0.f;
        #pragma unroll
        for (int i = 0; i < 2; i++) {
            #pragma unroll
            for (int ct = 0; ct < 4; ct++) {
                int n = col0 + ct * 16 + r;
                float w2v[DD_];
                #pragma unroll
                for (int d = 0; d < DD_; d++) w2v[d] = W2[n * DD_ + d];
                float b1 = bias[n];
                #pragma unroll
                for (int reg = 0; reg < 4; reg++) {
                    int m = row0 + w * 32 + i * 16 + q * 4 + reg;
                    if (m >= M) continue;
                    float val = fmaxf(acc[i][ct][reg] + b1, 0.f);
                    #pragma unroll
                    for (int d = 0; d < DD_; d++) s[i][reg][d] = fmaf(val, w2v[d], s[i][reg][d]);
                }
            }
        }
        #pragma unroll
        for (int i = 0; i < 2; i++)
            #pragma unroll
            for (int reg = 0; reg < 4; reg++)
                #pragma unroll
                for (int d = 0; d < DD_; d++) {
                    float v = s[i][reg][d];
                    v += __shfl_xor(v, 1);
                    v += __shfl_xor(v, 2);
                    v += __shfl_xor(v, 4);
                    v += __shfl_xor(v, 8);
                    if (r == 0) {
                        int m = row0 + w * 32 + i * 16 + q * 4 + reg;
                        if (m < M)
                            atomicAdd(&((float*)C0)[(long)m * (B_ * DD_) + zb * DD_ + d], v);
                    }
                }
        return;
    }

    #pragma unroll
    for (int i = 0; i < 2; i++) {
        #pragma unroll
        for (int ct = 0; ct < 4; ct++) {
            #pragma unroll
            for (int reg = 0; reg < 4; reg++) {
                int m = row0 + w * 32 + i * 16 + q * 4 + reg;
                int n = col0 + ct * 16 + r;
                if (m >= M || n >= N) continue;
                float v = acc[i][ct][reg];
                if (OUTMODE == OUT_SC) {
                    ((float*)C0)[(long)m * N + n] = v;
                } else if (OUTMODE == OUT_F1T) {
                    int b = m / 196, l = m - b * 196;
                    ((short*)C2)[((long)b * 512 + n) * 196 + l] = bf_hi(v);
                } else { // OUT_SPLIT
                    float v2 = v + bias[n];
                    long idx = (long)m * N + n;
                    short hi = bf_hi(v2);
                    ((short*)C0)[idx] = hi;
                    ((short*)C1)[idx] = bf_hi(v2 - bf2f_(hi));
                }
            }
        }
    }
}

// ---------------------------------------------------------------------------
// Edge MLP core: 64 edges x 256 units/block, K=600.
// ---------------------------------------------------------------------------
__device__ __forceinline__ void edge_core(
    char* sm, int be,
    const short* __restrict__ embedH, const int* __restrict__ edges,
    const short* __restrict__ Wr1T, const float* __restrict__ br1,
    const float* __restrict__ Wr2, const float* __restrict__ br2,
    float* __restrict__ prop)
{
    short (*As)[40] = (short(*)[40])sm;
    short (*Bs)[40] = (short(*)[40])(sm + 5120);
    int* src = (int*)(sm + 25600);
    int* dst = (int*)(sm + 25856);
    float (*part)[5] = (float(*)[5])(sm + 26112);
    int t = threadIdx.x;
    int e0 = be * 64;
    if (t < 64) {
        int e = e0 + t;
        src[t] = (e < E_) ? edges[e] : 0;
        dst[t] = (e < E_) ? edges[E_ + e] : 0;
    }
    __syncthreads();
    int lane = t & 63, w = t >> 6, q = lane >> 4, r = lane & 15;
    f32x4 zero4 = {0.f, 0.f, 0.f, 0.f};
    f32x4 acc[4][4];
    #pragma unroll
    for (int i = 0; i < 4; i++)
        #pragma unroll
        for (int j = 0; j < 4; j++) acc[i][j] = zero4;

    for (int ks = 0; ks < 19; ks++) {
        int k0 = ks * 32;
        {
            int arow = t >> 2, kc = (t & 3) * 8;
            int gk0 = k0 + kc;
            int sn = src[arow], dn = dst[arow];
            short tmp[8];
            if (gk0 + 8 <= 300) {
                const short* p = embedH + (long)sn * 300 + gk0;
                *(int2*)&tmp[0] = *(const int2*)p;
                *(int2*)&tmp[4] = *(const int2*)(p + 4);
            } else if (gk0 >= 300 && gk0 + 8 <= 600) {
                const short* p = embedH + (long)dn * 300 + (gk0 - 300);
                *(int2*)&tmp[0] = *(const int2*)p;
                *(int2*)&tmp[4] = *(const int2*)(p + 4);
            } else {
                #pragma unroll
                for (int j = 0; j < 8; j++) {
                    int gk = gk0 + j;
                    short v = 0;
                    if (gk < 300) v = embedH[(long)sn * 300 + gk];
                    else if (gk < 600) v = embedH[(long)dn * 300 + gk - 300];
                    tmp[j] = v;
                }
            }
            *(int4*)&As[arow][kc] = *(int4*)&tmp[0];
        }
        #pragma unroll
        for (int i = 0; i < 4; i++) {
            int n = i * 64 + (t >> 2), kc = (t & 3) * 8;
            int gk0 = k0 + kc;
            short tmp[8];
            if (gk0 + 8 <= 600) {
                const short* p = Wr1T + (long)n * 600 + gk0;
                *(int2*)&tmp[0] = *(const int2*)p;
                *(int2*)&tmp[4] = *(const int2*)(p + 4);
            } else {
                #pragma unroll
                for (int j = 0; j < 8; j++) tmp[j] = 0;
            }
            *(int4*)&Bs[n][kc] = *(int4*)&tmp[0];
        }
        __syncthreads();
        bf16x8 af[4], bfr[4];
        #pragma unroll
        for (int rt = 0; rt < 4; rt++) af[rt] = *(const bf16x8*)&As[rt * 16 + r][q * 8];
        #pragma unroll
        for (int ct = 0; ct < 4; ct++) bfr[ct] = *(const bf16x8*)&Bs[w * 64 + ct * 16 + r][q * 8];
        #pragma unroll
        for (int rt = 0; rt < 4; rt++)
            #pragma unroll
            for (int ct = 0; ct < 4; ct++)
                acc[rt][ct] = __builtin_amdgcn_mfma_f32_16x16x32_bf16(af[rt], bfr[ct], acc[rt][ct], 0, 0, 0);
        __syncthreads();
    }
    float b1v[4], w2v[4];
    #pragma unroll
    for (int ct = 0; ct < 4; ct++) {
        int u = w * 64 + ct * 16 + r;
        b1v[ct] = br1[u];
        w2v[ct] = Wr2[u];
    }
    #pragma unroll
    for (int rt = 0; rt < 4; rt++) {
        #pragma unroll
        for (int reg = 0; reg < 4; reg++) {
            float s = 0.f;
            #pragma unroll
            for (int ct = 0; ct < 4; ct++)
                s = fmaf(fmaxf(acc[rt][ct][reg] + b1v[ct], 0.f), w2v[ct], s);
            s += __shfl_xor(s, 1);
            s += __shfl_xor(s, 2);
            s += __shfl_xor(s, 4);
            s += __shfl_xor(s, 8);
            if (r == 0) part[rt * 16 + q * 4 + reg][w] = s;
        }
    }
    __syncthreads();
    if (t < 64 && e0 + t < E_) {
        float s = part[t][0] + part[t][1] + part[t][2] + part[t][3];
        atomicAdd(&prop[(long)src[t] * N_ + dst[t]], tanhf(s + br2[0]));
    }
}

// ---------------------------------------------------------------------------
// transpose+convert core
// ---------------------------------------------------------------------------
__device__ __forceinline__ void transconv_core(
    char* sm, int bx, int by,
    const float* __restrict__ in, short* __restrict__ outH, short* __restrict__ outL,
    int K, int N)
{
    float (*tile)[33] = (float(*)[33])sm;
    int k0 = bx * 32, n0 = by * 32;
    int t = threadIdx.x;
    int tr = t >> 5, tc = t & 31;
    #pragma unroll
    for (int i = 0; i < 4; i++) {
        int k = k0 + tr + i * 8, n = n0 + tc;
        tile[tr + i * 8][tc] = (k < K && n < N) ? in[(long)k * N + n] : 0.f;
    }
    __syncthreads();
    #pragma unroll
    for (int i = 0; i < 4; i++) {
        int n = n0 + tr + i * 8, k = k0 + tc;
        if (n < N && k < K) {
            float x = tile[tc][tr + i * 8];
            short hi = bf_hi(x);
            outH[(long)n * K + k] = hi;
            if (outL) outL[(long)n * K + k] = bf_hi(x - bf2f_(hi));
        }
    }
}

// ---------------------------------------------------------------------------
// K0: all prep (zero/init, pooled, conversions, transposes)
// ---------------------------------------------------------------------------
__global__ __launch_bounds__(256) void prep(
    float* __restrict__ prop, float* __restrict__ Ht0, const float* __restrict__ bf2,
    const float* __restrict__ feats, float* __restrict__ pooled,
    short* __restrict__ featsH, short* __restrict__ featsL,
    const float* __restrict__ embed, short* __restrict__ embH, short* __restrict__ embL,
    const float* __restrict__ W_key, const float* __restrict__ Wf1,
    short* __restrict__ WkfH, short* __restrict__ WkfL,
    const float* __restrict__ W_query, short* __restrict__ WqTh, short* __restrict__ WqTl,
    const float* __restrict__ Wr1, short* __restrict__ Wr1T)
{
    __shared__ __align__(16) char sm[SMEM_BYTES];
    int b = blockIdx.x, t = threadIdx.x;
    if (b < 977) {
        int i = (b * 256 + t) * 4;
        if (i < N_ * N_) { float4 z = {0.f, 0.f, 0.f, 0.f}; *(float4*)(prop + i) = z; }
    } else if (b < 1290) {
        int i = (b - 977) * 256 + t;
        if (i < N_ * B_ * DD_) Ht0[i] = bf2[i % DD_];
    } else if (b < 1418) {
        int idx = (b - 1290) * 256 + t;
        int bb = idx / FD_, f = idx % FD_;
        const float* p = feats + (long)bb * L_ * FD_ + f;
        float acc = 0.f;
        for (int l = 0; l < L_; l++) acc += p[(long)l * FD_];
        pooled[idx] = acc * (1.0f / L_);
    } else if (b < 4554) {
        long i = ((long)(b - 1418) * 256 + t) * 8;
        float4 v0 = *(const float4*)(feats + i);
        float4 v1 = *(const float4*)(feats + i + 4);
        float xs[8] = {v0.x, v0.y, v0.z, v0.w, v1.x, v1.y, v1.z, v1.w};
        short h[8], l8[8];
        #pragma unroll
        for (int j = 0; j < 8; j++) {
            h[j] = bf_hi(xs[j]);
            l8[j] = bf_hi(xs[j] - bf2f_(h[j]));
        }
        *(int4*)(featsH + i) = *(int4*)h;
        *(int4*)(featsL + i) = *(int4*)l8;
    } else if (b < 4847) {
        int i = ((b - 4554) * 256 + t) * 4;
        if (i < N_ * WD_) {
            float4 v = *(const float4*)(embed + i);
            float xs[4] = {v.x, v.y, v.z, v.w};
            short h[4], l4[4];
            #pragma unroll
            for (int j = 0; j < 4; j++) {
                h[j] = bf_hi(xs[j]);
                l4[j] = bf_hi(xs[j] - bf2f_(h[j]));
            }
            *(int2*)(embH + i) = *(int2*)h;
            *(int2*)(embL + i) = *(int2*)l4;
        }
    } else if (b < 5871) {
        int bb = b - 4847;
        transconv_core(sm, bb % 64, bb / 64, W_key, WkfH, WkfL, FD_, HD_);
    } else if (b < 6895) {
        int bb = b - 5871;
        transconv_core(sm, bb % 64, bb / 64, Wf1, WkfH + (size_t)512 * FD_, nullptr, FD_, HD_);
    } else if (b < 7055) {
        int bb = b - 6895;
        transconv_core(sm, bb % 10, bb / 10, W_query, WqTh, WqTl, WD_, HD_);
    } else {
        int bb = b - 7055;
        transconv_core(sm, bb % 19, bb / 19, Wr1, Wr1T, nullptr, 600, 256);
    }
}

// ---------------------------------------------------------------------------
// K1: keys(split) + F1(nonsplit) + queries + edge + clf  (1750 blocks)
// ---------------------------------------------------------------------------
__global__ __launch_bounds__(256) void mega1(
    const short* __restrict__ featsH, const short* __restrict__ featsL,
    const short* __restrict__ WkfH, const short* __restrict__ WkfL,
    const float* __restrict__ b_key, short* __restrict__ keysH, short* __restrict__ keysL,
    short* __restrict__ F1T,
    const short* __restrict__ embH, const short* __restrict__ embL,
    const short* __restrict__ WqTh, const short* __restrict__ WqTl,
    const float* __restrict__ b_query, short* __restrict__ qH, short* __restrict__ qL,
    const int* __restrict__ edges, const short* __restrict__ Wr1T,
    const float* __restrict__ br1, const float* __restrict__ Wr2,
    const float* __restrict__ br2, float* __restrict__ prop,
    const float* __restrict__ pooled, const float* __restrict__ W_clf,
    const float* __restrict__ b_clf, float* __restrict__ Pimg)
{
    __shared__ __align__(16) char sm[SMEM_BYTES];
    int b = blockIdx.x;
    if (b < 200) {
        mm_core<OUT_SPLIT, true>(sm, b & 7, b >> 3, 0,
            featsH, featsL, WkfH, WkfL, b_key,
            keysH, keysL, nullptr, nullptr, B_ * L_, 512, FD_, 0, FD_);
    } else if (b < 400) {
        int bb = b - 200;
        mm_core<OUT_F1T, false>(sm, bb & 7, bb >> 3, 0,
            featsH, nullptr, WkfH + (size_t)512 * FD_, nullptr, nullptr,
            nullptr, nullptr, F1T, nullptr, B_ * L_, 512, FD_, 0, FD_);
    } else if (b < 464) {
        int bb = b - 400;
        mm_core<OUT_SPLIT, true>(sm, bb & 7, bb >> 3, 0,
            embH, embL, WqTh, WqTl, b_query,
            qH, qL, nullptr, nullptr, N_, HD_, WD_, 0, WD_);
    } else if (b < 1246) {
        edge_core(sm, b - 464, embH, edges, Wr1T, br1, Wr2, br2, prop);
    } else {
        int bb = b - 1246;
        int ks = bb / 63, ix = bb % 63;
        int i = ix * 256 + threadIdx.x;
        if (i < B_ * NIMG_) {
            int bi = i / NIMG_, n = i % NIMG_;
            const float* p = pooled + (long)bi * FD_ + ks * 256;
            const float* w = W_clf + (long)(ks * 256) * NIMG_ + n;
            float acc = (ks == 0) ? b_clf[n] : 0.f;
            #pragma unroll 4
            for (int k = 0; k < 256; k++) acc = fmaf(p[k], w[(long)k * NIMG_], acc);
            Pimg[(long)ks * (B_ * NIMG_) + i] = acc;
        }
    }
}

// ---------------------------------------------------------------------------
// K2: scores GEMM into 2 k-chunk planes (1024) + softmax_img (4)
// ---------------------------------------------------------------------------
__global__ __launch_bounds__(256) void mega2(
    const short* __restrict__ qH, const short* __restrict__ qL,
    const short* __restrict__ keysH, const short* __restrict__ keysL,
    float* __restrict__ Pattn,
    const float* __restrict__ Pimg, float* __restrict__ out_img)
{
    __shared__ __align__(16) char sm[SMEM_BYTES];
    int b = blockIdx.x;
    if (b < 1024) {
        int bx = b & 3, by = (b >> 2) & 7, zb = (b >> 5) & 15, kc = b >> 9;
        const short* Bh = keysH + (long)zb * L_ * HD_;
        const short* Bl = keysL + (long)zb * L_ * HD_;
        float* C0 = Pattn + (long)kc * ((long)B_ * N_ * L_) + (long)zb * N_ * L_;
        mm_core<OUT_SC, true>(sm, bx, by, 0, qH, qL, Bh, Bl, nullptr,
                              C0, nullptr, nullptr, nullptr,
                              N_, L_, HD_, kc * 256, kc * 256 + 256);
    } else {
        int t = threadIdx.x;
        int wave = (b - 1024) * 4 + (t >> 6), lane = t & 63;
        if (wave >= B_) return;
        const int PER = (NIMG_ + 63) / 64;
        float v[PER];
        float m = -1e30f;
        int cnt = 0;
        for (int k = lane; k < NIMG_; k += 64) {
            float s = 0.f;
            #pragma unroll
            for (int ks = 0; ks < 8; ks++) s += Pimg[(long)ks * (B_ * NIMG_) + wave * NIMG_ + k];
            v[cnt] = s; m = fmaxf(m, s); cnt++;
        }
        #pragma unroll
        for (int off = 32; off; off >>= 1) m = fmaxf(m, __shfl_xor(m, off));
        float s = 0.f;
        for (int i = 0; i < cnt; i++) { v[i] = expf(v[i] - m); s += v[i]; }
        #pragma unroll
        for (int off = 32; off; off >>= 1) s += __shfl_xor(s, off);
        float inv = 1.f / s;
        cnt = 0;
        for (int k = lane; k < NIMG_; k += 64) out_img[(long)wave * NIMG_ + k] = v[cnt++] * inv;
    }
}

// ---------------------------------------------------------------------------
// K3: softmax over 196 of (P0+P1); writes out_attn fp32 + attnH bf16
// ---------------------------------------------------------------------------
__global__ void softmax_attn(const float* __restrict__ P0, const float* __restrict__ P1,
                             float* __restrict__ X, short* __restrict__ Xb, int rows)
{
    int gid = blockIdx.x * blockDim.x + threadIdx.x;
    int wave = gid >> 6, lane = gid & 63;
    if (wave >= rows) return;
    const int PER = (L_ + 63) / 64;
    float v[PER];
    float m = -1e30f;
    int cnt = 0;
    for (int k = lane; k < L_; k += 64) {
        long idx = (long)wave * L_ + k;
        v[cnt] = P0[idx] + P1[idx];
        m = fmaxf(m, v[cnt]); cnt++;
    }
    #pragma unroll
    for (int off = 32; off; off >>= 1) m = fmaxf(m, __shfl_xor(m, off));
    float s = 0.f;
    for (int i = 0; i < cnt; i++) { v[i] = expf(v[i] - m); s += v[i]; }
    #pragma unroll
    for (int off = 32; off; off >>= 1) s += __shfl_xor(s, off);
    float inv = 1.f / s;
    cnt = 0;
    for (int k = lane; k < L_; k += 64) {
        float val = v[cnt++] * inv;
        long idx = (long)wave * L_ + k;
        X[idx] = val;
        Xb[idx] = bf_hi(val);
    }
}

// ---------------------------------------------------------------------------
// K4: h1 GEMM with fused h0 epilogue (atomic into bf2-initialized Ht0)
// ---------------------------------------------------------------------------
__global__ __launch_bounds__(256) void h0gemm(
    const short* __restrict__ attnH, const short* __restrict__ F1T,
    const float* __restrict__ bf1, const float* __restrict__ Wf2,
    float* __restrict__ Ht0)
{
    __shared__ __align__(16) char sm[SMEM_BYTES];
    int b = blockIdx.x;
    int bx = b & 7, by = (b >> 3) & 7, zb = b >> 6;
    const short* Ap = attnH + (long)zb * N_ * L_;
    const short* Bp = F1T + (long)zb * HD_ * L_;
    mm_core<OUT_H0, false>(sm, bx, by, zb, Ap, nullptr, Bp, nullptr,
                           bf1, Ht0, nullptr, nullptr, Wf2,
                           N_, HD_, L_, 0, L_);
}

// ---------------------------------------------------------------------------
// Recurrence step, one thread per output element (H [N][B*D=80]).
// ---------------------------------------------------------------------------
__global__ __launch_bounds__(320) void step_kernel(
    const float* __restrict__ prop, const float* __restrict__ Hin,
    float* __restrict__ Hout,
    const float* __restrict__ W_ih, const float* __restrict__ b_ih,
    const float* __restrict__ W_hh, const float* __restrict__ b_hh)
{
    __shared__ float msg[4][80];
    int t = threadIdx.x;
    int nl = t / 80, c = t - nl * 80;
    int n = blockIdx.x * 4 + nl;
    const float* pr = prop + (long)n * N_;
    const float* hc = Hin + c;
    float acc = 0.f;
    #pragma unroll 4
    for (int m4 = 0; m4 < N_; m4 += 4) {
        float4 pv = *(const float4*)(pr + m4);
        acc = fmaf(pv.x, hc[(long)(m4 + 0) * 80], acc);
        acc = fmaf(pv.y, hc[(long)(m4 + 1) * 80], acc);
        acc = fmaf(pv.z, hc[(long)(m4 + 2) * 80], acc);
        acc = fmaf(pv.w, hc[(long)(m4 + 3) * 80], acc);
    }
    msg[nl][c] = tanhf(acc);
    __syncthreads();
    if (t < 64) {
        int nl2 = t >> 4, b = t & 15;
        int n2 = blockIdx.x * 4 + nl2;
        float xv[DD_], h[DD_];
        #pragma unroll
        for (int j = 0; j < DD_; j++) {
            xv[j] = msg[nl2][b * DD_ + j];
            h[j] = Hin[(long)n2 * 80 + b * DD_ + j];
        }
        float gi[3 * DD_], gh[3 * DD_];
        #pragma unroll
        for (int g = 0; g < 3 * DD_; g++) {
            float a = b_ih[g], cc = b_hh[g];
            #pragma unroll
            for (int k = 0; k < DD_; k++) {
                a = fmaf(xv[k], W_ih[g * DD_ + k], a);
                cc = fmaf(h[k], W_hh[g * DD_ + k], cc);
            }
            gi[g] = a; gh[g] = cc;
        }
        #pragma unroll
        for (int j = 0; j < DD_; j++) {
            float rr = 1.f / (1.f + expf(-(gi[j] + gh[j])));
            float zz = 1.f / (1.f + expf(-(gi[DD_ + j] + gh[DD_ + j])));
            float nn2 = tanhf(gi[2 * DD_ + j] + rr * gh[2 * DD_ + j]);
            Hout[(long)n2 * 80 + b * DD_ + j] = (1.f - zz) * nn2 + zz * h[j];
        }
    }
}

__global__ void out_kernel(const float* __restrict__ ht, const float* __restrict__ Wo1,
                           const float* __restrict__ bo1, const float* __restrict__ Wo2,
                           const float* __restrict__ bo2, float* __restrict__ logits, int rows)
{
    int gid = blockIdx.x * blockDim.x + threadIdx.x;
    int wave = gid >> 6, lane = gid & 63;
    if (wave >= rows) return;
    int b = wave / N_, n = wave % N_;
    float x[DD_];
    #pragma unroll
    for (int i = 0; i < DD_; i++) x[i] = ht[(long)n * (B_ * DD_) + b * DD_ + i];
    float acc = 0.f;
    for (int j = lane; j < HD_; j += 64) {
        float h = bo1[j];
        #pragma unroll
        for (int d = 0; d < DD_; d++) h = fmaf(x[d], Wo1[d * HD_ + j], h);
        h = fmaxf(h, 0.f);
        acc = fmaf(h, Wo2[j], acc);
    }
    #pragma unroll
    for (int off = 32; off; off >>= 1) acc += __shfl_down(acc, off);
    if (lane == 0) logits[wave] = acc + bo2[0];
}

// ---------------------------------------------------------------------------
extern "C" void kernel_launch(void* const* d_in, const int* in_sizes, int n_in,
                              void* d_out, int out_size, void* d_ws, size_t ws_size,
                              hipStream_t stream)
{
    const float* feats   = (const float*)d_in[0];
    const float* embed   = (const float*)d_in[1];
    const int*   edges   = (const int*)  d_in[2];
    const float* W_key   = (const float*)d_in[3];
    const float* b_key   = (const float*)d_in[4];
    const float* W_query = (const float*)d_in[5];
    const float* b_query = (const float*)d_in[6];
    const float* Wf1     = (const float*)d_in[7];
    const float* bf1     = (const float*)d_in[8];
    const float* Wf2     = (const float*)d_in[9];
    const float* bf2     = (const float*)d_in[10];
    const float* Wr1     = (const float*)d_in[11];
    const float* br1     = (const float*)d_in[12];
    const float* Wr2     = (const float*)d_in[13];
    const float* br2     = (const float*)d_in[14];
    const float* Wo1     = (const float*)d_in[15];
    const float* bo1     = (const float*)d_in[16];
    const float* Wo2     = (const float*)d_in[17];
    const float* bo2     = (const float*)d_in[18];
    const float* W_ih    = (const float*)d_in[19];
    const float* b_ih    = (const float*)d_in[20];
    const float* W_hh    = (const float*)d_in[21];
    const float* b_hh    = (const float*)d_in[22];
    const float* W_clf   = (const float*)d_in[23];
    const float* b_clf   = (const float*)d_in[24];

    float* out_logits = (float*)d_out;
    float* out_attn   = out_logits + B_ * N_;
    float* out_img    = out_attn + (long)B_ * N_ * L_;

    char* p = (char*)d_ws;
    auto alloc = [&](size_t bytes) { void* r = (void*)p; p += (bytes + 255) & ~(size_t)255; return r; };
    float* pooled  = (float*)alloc((size_t)B_ * FD_ * 4);
    short* featsH  = (short*)alloc((size_t)B_ * L_ * FD_ * 2);
    short* featsL  = (short*)alloc((size_t)B_ * L_ * FD_ * 2);
    short* WkfH    = (short*)alloc((size_t)1024 * FD_ * 2);
    short* WkfL    = (short*)alloc((size_t)512 * FD_ * 2);
    short* WqTh    = (short*)alloc((size_t)HD_ * WD_ * 2);
    short* WqTl    = (short*)alloc((size_t)HD_ * WD_ * 2);
    short* Wr1T    = (short*)alloc((size_t)256 * 600 * 2);
    short* embH    = (short*)alloc((size_t)N_ * WD_ * 2);
    short* embL    = (short*)alloc((size_t)N_ * WD_ * 2);
    short* keysH   = (short*)alloc((size_t)B_ * L_ * HD_ * 2);
    short* keysL   = (short*)alloc((size_t)B_ * L_ * HD_ * 2);
    short* qH      = (short*)alloc((size_t)N_ * HD_ * 2);
    short* qL      = (short*)alloc((size_t)N_ * HD_ * 2);
    short* attnH   = (short*)alloc((size_t)B_ * N_ * L_ * 2);
    short* F1T     = (short*)alloc((size_t)B_ * HD_ * L_ * 2);
    float* prop    = (float*)alloc((size_t)N_ * N_ * 4);
    float* Ht0     = (float*)alloc((size_t)N_ * B_ * DD_ * 4);
    float* Ht1     = (float*)alloc((size_t)N_ * B_ * DD_ * 4);
    float* Pimg    = (float*)alloc((size_t)8 * B_ * NIMG_ * 4);
    float* Pattn   = (float*)alloc((size_t)2 * B_ * N_ * L_ * 4);

    // K0: all prep
    prep<<<7207, 256, 0, stream>>>(prop, Ht0, bf2, feats, pooled, featsH, featsL,
                                   embed, embH, embL, W_key, Wf1, WkfH, WkfL,
                                   W_query, WqTh, WqTl, Wr1, Wr1T);

    // K1: keys + F1 + queries + edge + clf
    mega1<<<1750, 256, 0, stream>>>(featsH, featsL, WkfH, WkfL, b_key, keysH, keysL, F1T,
                                    embH, embL, WqTh, WqTl, b_query, qH, qL,
                                    edges, Wr1T, br1, Wr2, br2, prop,
                                    pooled, W_clf, b_clf, Pimg);

    // K2: scores (2 k-planes) + softmax_img
    mega2<<<1028, 256, 0, stream>>>(qH, qL, keysH, keysL, Pattn, Pimg, out_img);

    // K3: softmax over 196 (sums planes), writes out_attn + attnH
    softmax_attn<<<(B_ * N_ * 64 + 255) / 256, 256, 0, stream>>>(
        Pattn, Pattn + (long)B_ * N_ * L_, out_attn, attnH, B_ * N_);

    // K4: h1 GEMM with fused h0 epilogue
    h0gemm<<<1024, 256, 0, stream>>>(attnH, F1T, bf1, Wf2, Ht0);

    // K5..K10: recurrence + output head
    {
        float* hin = Ht0;
        float* hout = Ht1;
        for (int step = 0; step < TMAX_; step++) {
            step_kernel<<<N_ / 4, 320, 0, stream>>>(prop, hin, hout,
                                                    W_ih, b_ih, W_hh, b_hh);
            float* tmp = hin; hin = hout; hout = tmp;
        }
        out_kernel<<<(B_ * N_ * 64 + 255) / 256, 256, 0, stream>>>(hin, Wo1, bo1, Wo2, bo2,
                                                                   out_logits, B_ * N_);
    }
}